// Round 17
// baseline (108.026 us; speedup 1.0000x reference)
//
#include <hip/hip_runtime.h>
#include <hip/hip_bf16.h>

typedef short bf16x8 __attribute__((ext_vector_type(8)));
typedef float f32x4  __attribute__((ext_vector_type(4)));

#define B_    2
#define S_    2048
#define H_    32
#define HKV_  8
#define D_    128
#define QBLK  64      // fallback kernel's q-block
#define QBLK2 128     // main kernel's q-block (32 q/wave x 4 waves)
#define KVB   64      // main kernel's kv-tile
// head_dim^-0.5 * log2(e): scores come out in log2 units -> use exp2
#define SCALE 0.1275431741f

static __device__ inline float exp2_fast(float x) {
    return __builtin_amdgcn_exp2f(x);   // v_exp_f32: D = 2^S0
}

static __device__ inline unsigned short f2bf(float f) {
    unsigned u = __builtin_bit_cast(unsigned, f);
    u += 0x7fffu + ((u >> 16) & 1u);   // round-to-nearest-even
    return (unsigned short)(u >> 16);
}
static __device__ inline unsigned pk2(float a, float b) {
    return (unsigned)f2bf(a) | ((unsigned)f2bf(b) << 16);
}
static __device__ inline short cvt_bf(float f) {
    __hip_bfloat16 h = __float2bfloat16(f);
    return __builtin_bit_cast(short, h);
}
static __device__ inline void gload16(const unsigned char* g, unsigned char* l) {
    __builtin_amdgcn_global_load_lds(
        (const __attribute__((address_space(1))) void*)g,
        (__attribute__((address_space(3))) void*)l, 16, 0, 0);
}

// ---------------- pre-pass: K -> bf16 pre-swizzled LDS image ----------------
__global__ __launch_bounds__(256) void prep_k(const float* __restrict__ Kg,
                                              unsigned char* __restrict__ Kb) {
    const int s   = blockIdx.x * 256 + threadIdx.x;     // 524288 16B-slots
    const int seg = s & 15;
    const int kv  = (s >> 4) & (S_ - 1);
    const int bhk = s >> 15;
    const int hk  = bhk & (HKV_ - 1);
    const int b   = bhk >> 3;
    const float* src = Kg + ((size_t)(b * S_ + kv) * HKV_ + hk) * D_ + seg * 8;
    float4 x0 = *(const float4*)(src);
    float4 x1 = *(const float4*)(src + 4);
    uint4 u = { pk2(x0.x, x0.y), pk2(x0.z, x0.w), pk2(x1.x, x1.y), pk2(x1.z, x1.w) };
    *(uint4*)(Kb + ((size_t)(b * HKV_ + hk) * S_ + kv) * 256 + ((seg * 16) ^ ((kv & 7) << 4))) = u;
}

// ---- pre-pass: V -> bf16 transposed+permuted tile image (64kv, 128x80) ----
// Vb[(b*HKV+hk)*32 + tile]: 128 x 80-short image (cols 64..79 pad).
// col = chunk*32 + kp (chunk = kv32-block); kp->kv perm within chunk:
// kv = chunk*32 + ((kp>>2)&1)*16 + (kp>>3)*4 + (kp&3)
__global__ __launch_bounds__(256) void prep_v(const float* __restrict__ Vg,
                                              unsigned short* __restrict__ Vb) {
    const int blk     = blockIdx.x;       // B*HKV*32*4 = 2048
    const int quarter = blk & 3;
    const int tile    = (blk >> 2) & 31;
    const int hk      = (blk >> 7) & (HKV_ - 1);
    const int b       = blk >> 10;
    const int t       = threadIdx.x;
    const int kp0     = (t & 7) * 8;                 // 0..56
    const int d       = (t >> 3) + quarter * 32;     // 0..127
    const int kv0     = tile * KVB;
    unsigned short tmp[8];
#pragma unroll
    for (int j = 0; j < 8; ++j) {
        const int kp    = kp0 + j;
        const int chunk = kp >> 5;
        const int wi    = kp & 31;
        const int kv    = chunk * 32 + (((wi >> 2) & 1) << 4) + ((wi >> 3) << 2) + (wi & 3);
        tmp[j] = f2bf(Vg[((size_t)(b * S_ + kv0 + kv) * HKV_ + hk) * D_ + d]);
    }
    unsigned short* dst = Vb + ((size_t)(b * HKV_ + hk) * 32 + tile) * (128 * 80) + d * 80 + kp0;
    *(uint4*)dst = *(uint4*)tmp;
}

// ------------------------------ main kernel --------------------------------
// 512 uniform blocks: block (pair,hb) runs two sequential kv-sweeps:
// job0 = q-tile (15-pair), job1 = q-tile pair -> 34 staged 64-kv tiles each.
// 2 blocks/CU (72KB LDS), single-barrier pipeline (R12 base).
// R16: chunk-split iteration -> PV(chunk0) overlaps softmax(chunk1);
//      chunk1 skipped on gate tile; job1 tile-0 prefetched in job0's tail.
__global__ __launch_bounds__(256, 2) void fattn4(
        const float* __restrict__ Qg, const unsigned char* __restrict__ Kb,
        const unsigned char* __restrict__ Vb, float* __restrict__ Og) {
    // per buffer: K 16384B (64x256 swizzled) + V 20480B (128x80 shorts)
    __shared__ __align__(16) unsigned char lds[2 * 36864];

    const int tid  = threadIdx.x;
    const int lane = tid & 63;
    const int w    = tid >> 6;
    const int m    = lane & 15;
    const int g    = lane >> 4;
    const int lane16 = lane * 16;
    const int sw   = (m & 7) << 4;

    const int bid  = blockIdx.x;          // 512 = 8 pairs x 64 (b,h)
    const int pair = bid >> 6;            // 0..7
    const int hb   = bid & 63;
    const int h    = hb & (H_ - 1);
    const int b    = hb >> 5;
    const int hk   = h >> 2;

    const unsigned char* KbH = Kb + (size_t)(b * HKV_ + hk) * S_ * 256;
    const unsigned char* VbH = Vb + (size_t)(b * HKV_ + hk) * 32 * 20480;
    const float* QgH = Qg + (size_t)(b * S_ * H_ + h) * D_;

#define STAGE(kt, cbuf) do {                                                  \
        const unsigned char* KbT = KbH + (size_t)(kt) * 16384;                \
        const unsigned char* VbT = VbH + (size_t)(kt) * 20480;                \
        unsigned char* dK = lds + (cbuf) * 36864;                             \
        unsigned char* dV = dK + 16384;                                       \
        gload16(KbT + (w * 4 + 0) * 1024 + lane16, dK + (w * 4 + 0) * 1024);  \
        gload16(KbT + (w * 4 + 1) * 1024 + lane16, dK + (w * 4 + 1) * 1024);  \
        gload16(KbT + (w * 4 + 2) * 1024 + lane16, dK + (w * 4 + 2) * 1024);  \
        gload16(KbT + (w * 4 + 3) * 1024 + lane16, dK + (w * 4 + 3) * 1024);  \
        gload16(VbT + (w * 5 + 0) * 1024 + lane16, dV + (w * 5 + 0) * 1024);  \
        gload16(VbT + (w * 5 + 1) * 1024 + lane16, dV + (w * 5 + 1) * 1024);  \
        gload16(VbT + (w * 5 + 2) * 1024 + lane16, dV + (w * 5 + 2) * 1024);  \
        gload16(VbT + (w * 5 + 3) * 1024 + lane16, dV + (w * 5 + 3) * 1024);  \
        gload16(VbT + (w * 5 + 4) * 1024 + lane16, dV + (w * 5 + 4) * 1024);  \
    } while (0)

// rare-rescale: reduce pmax -> dm per q, rescale accumulated state, shift
// slabs [S_LO, S_HI) into the new frame. (_Pragma inside macro body is OK.)
#define GUARD(pmaxv, S_LO, S_HI) do {                                         \
        if (__any((pmaxv) > 12.0f)) {                                         \
            float dm = fmaxf((pmaxv), __shfl_xor((pmaxv), 16));               \
            dm = fmaxf(dm, __shfl_xor(dm, 32));                               \
            dm = fmaxf(dm, 0.0f);                                             \
            const float corr = exp2_fast(-dm);                                \
            lsumA *= corr; lsumB *= corr;                                     \
            float cj[4];                                                      \
            _Pragma("unroll")                                                 \
            for (int jj = 0; jj < 4; ++jj) cj[jj] = __shfl(corr, g * 4 + jj); \
            _Pragma("unroll")                                                 \
            for (int i = 0; i < 8; ++i)                                       \
                _Pragma("unroll")                                             \
                for (int jj = 0; jj < 4; ++jj) {                              \
                    oaccA[i][jj] *= cj[jj];                                   \
                    oaccB[i][jj] *= cj[jj];                                   \
                }                                                             \
            m_run += dm;                                                      \
            _Pragma("unroll")                                                 \
            for (int s = (S_LO); s < (S_HI); ++s)                             \
                _Pragma("unroll")                                             \
                for (int jj = 0; jj < 4; ++jj) {                              \
                    sA[s][jj] -= dm; sB[s][jj] -= dm;                         \
                }                                                             \
        }                                                                     \
    } while (0)

    int cur = 0;
    STAGE(0, 0);
    asm volatile("s_waitcnt vmcnt(0)" ::: "memory");
    __builtin_amdgcn_s_barrier();

    for (int job = 0; job < 2; ++job) {
        const int qt    = (job == 0) ? (15 - pair) : pair;
        const int qB    = qt * QBLK2;
        const int q0w   = qB + w * 32;
        const int qA    = q0w + m;
        const int qgate = q0w + 31;

        // ---- Q fragments, pre-scaled by SCALE (includes log2e) ----
        bf16x8 qfA[4], qfB[4];
        {
            const float* qrowA = QgH + (size_t)qA * H_ * D_;
            const float* qrowB = qrowA + (size_t)16 * H_ * D_;
#pragma unroll
            for (int db = 0; db < 4; ++db) {
                const float* pA = qrowA + db * 32 + g * 8;
                const float* pB = qrowB + db * 32 + g * 8;
                float4 a0 = *(const float4*)(pA);
                float4 a1 = *(const float4*)(pA + 4);
                float4 b0 = *(const float4*)(pB);
                float4 b1 = *(const float4*)(pB + 4);
                bf16x8 qa, qb;
                qa[0] = cvt_bf(a0.x * SCALE); qa[1] = cvt_bf(a0.y * SCALE);
                qa[2] = cvt_bf(a0.z * SCALE); qa[3] = cvt_bf(a0.w * SCALE);
                qa[4] = cvt_bf(a1.x * SCALE); qa[5] = cvt_bf(a1.y * SCALE);
                qa[6] = cvt_bf(a1.z * SCALE); qa[7] = cvt_bf(a1.w * SCALE);
                qb[0] = cvt_bf(b0.x * SCALE); qb[1] = cvt_bf(b0.y * SCALE);
                qb[2] = cvt_bf(b0.z * SCALE); qb[3] = cvt_bf(b0.w * SCALE);
                qb[4] = cvt_bf(b1.x * SCALE); qb[5] = cvt_bf(b1.y * SCALE);
                qb[6] = cvt_bf(b1.z * SCALE); qb[7] = cvt_bf(b1.w * SCALE);
                qfA[db] = qa; qfB[db] = qb;
            }
        }

        f32x4 oaccA[8], oaccB[8];
#pragma unroll
        for (int i = 0; i < 8; ++i) {
            oaccA[i] = (f32x4){0.f, 0.f, 0.f, 0.f};
            oaccB[i] = (f32x4){0.f, 0.f, 0.f, 0.f};
        }
        float m_run = 4.0f, lsumA = 0.f, lsumB = 0.f;

        const int nt = 2 * (qt + 1);

        for (int t = 0; t < nt; ++t) {
            const int kv0 = t * KVB;
            if (t + 1 < nt)       STAGE(t + 1, cur ^ 1);
            else if (job == 0)    STAGE(0, cur ^ 1);   // prefetch job1 tile 0

            if (kv0 <= qgate) {
                const unsigned char* cK = lds + cur * 36864;
                const unsigned char* cV = cK + 16384;

                // ---- S^T = K · Q^T, all 4 slabs, C pre-loaded with -m_run ----
                const f32x4 cinit = (f32x4){-m_run, -m_run, -m_run, -m_run};
                f32x4 sA[4], sB[4];
#pragma unroll
                for (int s = 0; s < 4; ++s) { sA[s] = cinit; sB[s] = cinit; }
                __builtin_amdgcn_s_setprio(1);
#pragma unroll
                for (int s = 0; s < 4; ++s) {
#pragma unroll
                    for (int db = 0; db < 4; ++db) {
                        const int co = (db * 64 + g * 16) ^ sw;
                        bf16x8 kf = *(const bf16x8*)(cK + (m + 16 * s) * 256 + co);
                        sA[s] = __builtin_amdgcn_mfma_f32_16x16x32_bf16(kf, qfA[db], sA[s], 0, 0, 0);
                        sB[s] = __builtin_amdgcn_mfma_f32_16x16x32_bf16(kf, qfB[db], sB[s], 0, 0, 0);
                    }
                }
                __builtin_amdgcn_s_setprio(0);

                // ================= chunk 0 (kv0 .. kv0+31, slabs 0,1) ========
                if (kv0 + 31 > q0w) {                 // diagonal: causal mask
                    const int qBrow = qA + 16;
#pragma unroll
                    for (int s = 0; s < 2; ++s)
#pragma unroll
                        for (int jj = 0; jj < 4; ++jj) {
                            const int kva = kv0 + 16 * s + g * 4 + jj;
                            if (kva > qA)    sA[s][jj] = -1e30f;
                            if (kva > qBrow) sB[s][jj] = -1e30f;
                        }
                }
                {
                    float pmax = -1e30f;
#pragma unroll
                    for (int s = 0; s < 2; ++s)
#pragma unroll
                        for (int jj = 0; jj < 4; ++jj)
                            pmax = fmaxf(pmax, fmaxf(sA[s][jj], sB[s][jj]));
                    GUARD(pmax, 0, 4);
                }
#pragma unroll
                for (int s = 0; s < 2; ++s)
#pragma unroll
                    for (int jj = 0; jj < 4; ++jj) {
                        sA[s][jj] = exp2_fast(sA[s][jj]);
                        sB[s][jj] = exp2_fast(sB[s][jj]);
                    }
#pragma unroll
                for (int s = 0; s < 2; ++s) {
                    lsumA += (sA[s][0] + sA[s][1]) + (sA[s][2] + sA[s][3]);
                    lsumB += (sB[s][0] + sB[s][1]) + (sB[s][2] + sB[s][3]);
                }
                bf16x8 paA0, paB0;
#pragma unroll
                for (int jj = 0; jj < 4; ++jj) {
                    paA0[jj] = cvt_bf(sA[0][jj]); paA0[4 + jj] = cvt_bf(sA[1][jj]);
                    paB0[jj] = cvt_bf(sB[0][jj]); paB0[4 + jj] = cvt_bf(sB[1][jj]);
                }

                // ---- PV chunk0 (MFMA pipe; chunk1 softmax fills VALU) ----
                __builtin_amdgcn_s_setprio(1);
#pragma unroll
                for (int db8 = 0; db8 < 8; ++db8) {
                    const unsigned char* vrow = cV + (db8 * 16 + m) * 160 + g * 16;
                    bf16x8 vf0 = *(const bf16x8*)(vrow);
                    oaccA[db8] = __builtin_amdgcn_mfma_f32_16x16x32_bf16(paA0, vf0, oaccA[db8], 0, 0, 0);
                    oaccB[db8] = __builtin_amdgcn_mfma_f32_16x16x32_bf16(paB0, vf0, oaccB[db8], 0, 0, 0);
                }
                __builtin_amdgcn_s_setprio(0);

                // ================= chunk 1 (kv0+32 .. kv0+63, slabs 2,3) =====
                // wave-uniform skip: whole chunk above the wave's gate
                if (kv0 + 32 <= qgate) {
                    if (kv0 + 63 > q0w) {             // diagonal: causal mask
                        const int qBrow = qA + 16;
#pragma unroll
                        for (int s = 2; s < 4; ++s)
#pragma unroll
                            for (int jj = 0; jj < 4; ++jj) {
                                const int kva = kv0 + 16 * s + g * 4 + jj;
                                if (kva > qA)    sA[s][jj] = -1e30f;
                                if (kva > qBrow) sB[s][jj] = -1e30f;
                            }
                    }
                    {
                        float pmax = -1e30f;
#pragma unroll
                        for (int s = 2; s < 4; ++s)
#pragma unroll
                            for (int jj = 0; jj < 4; ++jj)
                                pmax = fmaxf(pmax, fmaxf(sA[s][jj], sB[s][jj]));
                        GUARD(pmax, 2, 4);
                    }
#pragma unroll
                    for (int s = 2; s < 4; ++s)
#pragma unroll
                        for (int jj = 0; jj < 4; ++jj) {
                            sA[s][jj] = exp2_fast(sA[s][jj]);
                            sB[s][jj] = exp2_fast(sB[s][jj]);
                        }
#pragma unroll
                    for (int s = 2; s < 4; ++s) {
                        lsumA += (sA[s][0] + sA[s][1]) + (sA[s][2] + sA[s][3]);
                        lsumB += (sB[s][0] + sB[s][1]) + (sB[s][2] + sB[s][3]);
                    }
                    bf16x8 paA1, paB1;
#pragma unroll
                    for (int jj = 0; jj < 4; ++jj) {
                        paA1[jj] = cvt_bf(sA[2][jj]); paA1[4 + jj] = cvt_bf(sA[3][jj]);
                        paB1[jj] = cvt_bf(sB[2][jj]); paB1[4 + jj] = cvt_bf(sB[3][jj]);
                    }
                    __builtin_amdgcn_s_setprio(1);
#pragma unroll
                    for (int db8 = 0; db8 < 8; ++db8) {
                        const unsigned char* vrow = cV + (db8 * 16 + m) * 160 + g * 16;
                        bf16x8 vf1 = *(const bf16x8*)(vrow + 64);
                        oaccA[db8] = __builtin_amdgcn_mfma_f32_16x16x32_bf16(paA1, vf1, oaccA[db8], 0, 0, 0);
                        oaccB[db8] = __builtin_amdgcn_mfma_f32_16x16x32_bf16(paB1, vf1, oaccB[db8], 0, 0, 0);
                    }
                    __builtin_amdgcn_s_setprio(0);
                }
            }

            // drain this iter's prefetch (hidden under compute), single barrier
            asm volatile("s_waitcnt vmcnt(0)" ::: "memory");
            __builtin_amdgcn_s_barrier();
            cur ^= 1;
        }

        // ---- epilogue: deferred l reductions + O write for this job ----
        lsumA += __shfl_xor(lsumA, 16); lsumA += __shfl_xor(lsumA, 32);
        lsumB += __shfl_xor(lsumB, 16); lsumB += __shfl_xor(lsumB, 32);
        const float rA = 1.0f / lsumA, rB = 1.0f / lsumB;
        float rsA[4], rsB[4];
#pragma unroll
        for (int jj = 0; jj < 4; ++jj) {
            rsA[jj] = __shfl(rA, g * 4 + jj);
            rsB[jj] = __shfl(rB, g * 4 + jj);
        }
#pragma unroll
        for (int db8 = 0; db8 < 8; ++db8) {
#pragma unroll
            for (int jj = 0; jj < 4; ++jj) {
                const int qrA = q0w + g * 4 + jj;
                Og[(size_t)((b * S_ + qrA) * H_ + h) * D_ + db8 * 16 + m]
                    = oaccA[db8][jj] * rsA[jj];
                Og[(size_t)((b * S_ + qrA + 16) * H_ + h) * D_ + db8 * 16 + m]
                    = oaccB[db8][jj] * rsB[jj];
            }
        }
        // job1's tile 0 already staged & drained; buffers safe to reuse.
    }
#undef GUARD
#undef STAGE
}

// ------------------------- fallback (round-0 kernel) ------------------------
__global__ __launch_bounds__(256) void fattn_fallback(
        const float* __restrict__ Qg, const float* __restrict__ Kg,
        const float* __restrict__ Vg, float* __restrict__ Og) {
    __shared__ __align__(16) unsigned char  sK[32 * 256];
    __shared__ __align__(16) unsigned short sV[128 * 40];
    const int tid  = threadIdx.x;
    const int lane = tid & 63;
    const int w    = tid >> 6;
    const int m    = lane & 15;
    const int g    = lane >> 4;
    const int SQ = S_ / QBLK;
    const int bid = blockIdx.x;
    const int qt  = bid % SQ;
    const int h   = (bid / SQ) % H_;
    const int b   = bid / (SQ * H_);
    const int hk  = h >> 2;
    const int qB    = qt * QBLK;
    const int q0w   = qB + w * 16;
    const int q_abs = q0w + m;
    const float SC = 0.08838834764831845f;
    bf16x8 qf[4];
    {
        const float* qrow = Qg + (size_t)((b * S_ + q_abs) * H_ + h) * D_;
#pragma unroll
        for (int db = 0; db < 4; ++db) {
            const float* p = qrow + db * 32 + g * 8;
            float4 a = *(const float4*)(p);
            float4 c = *(const float4*)(p + 4);
            bf16x8 q8;
            q8[0] = (short)f2bf(a.x * SC); q8[1] = (short)f2bf(a.y * SC);
            q8[2] = (short)f2bf(a.z * SC); q8[3] = (short)f2bf(a.w * SC);
            q8[4] = (short)f2bf(c.x * SC); q8[5] = (short)f2bf(c.y * SC);
            q8[6] = (short)f2bf(c.z * SC); q8[7] = (short)f2bf(c.w * SC);
            qf[db] = q8;
        }
    }
    f32x4 oacc[8];
#pragma unroll
    for (int i = 0; i < 8; ++i) oacc[i] = (f32x4){0.f, 0.f, 0.f, 0.f};
    float m_run = -1e30f, lsum = 0.f;
    const int nt = (qB + QBLK) / 32;
    for (int t = 0; t < nt; ++t) {
        const int kv0 = t * 32;
        __syncthreads();
        {
            const int r = tid >> 3, seg = tid & 7;
            const float* src = Kg + (size_t)((b * S_ + kv0 + r) * HKV_ + hk) * D_ + seg * 16;
            float4 x0 = *(const float4*)(src + 0);
            float4 x1 = *(const float4*)(src + 4);
            float4 x2 = *(const float4*)(src + 8);
            float4 x3 = *(const float4*)(src + 12);
            uint4 u0 = { pk2(x0.x,x0.y), pk2(x0.z,x0.w), pk2(x1.x,x1.y), pk2(x1.z,x1.w) };
            uint4 u1 = { pk2(x2.x,x2.y), pk2(x2.z,x2.w), pk2(x3.x,x3.y), pk2(x3.z,x3.w) };
            const int colb = seg * 32;
            const int swz  = (r & 7) << 4;
            *(uint4*)(sK + r * 256 + ((colb     ) ^ swz)) = u0;
            *(uint4*)(sK + r * 256 + ((colb + 16) ^ swz)) = u1;
        }
        {
            const int kv = tid & 31, d0 = (tid >> 5) * 16;
            const int kp = (((kv & 15) >> 2) << 3) + ((kv >> 4) << 2) + (kv & 3);
            const float* src = Vg + (size_t)((b * S_ + kv0 + kv) * HKV_ + hk) * D_ + d0;
#pragma unroll
            for (int i = 0; i < 4; ++i) {
                float4 x = *(const float4*)(src + i * 4);
                const int d = d0 + i * 4;
                sV[(d + 0) * 40 + kp] = f2bf(x.x);
                sV[(d + 1) * 40 + kp] = f2bf(x.y);
                sV[(d + 2) * 40 + kp] = f2bf(x.z);
                sV[(d + 3) * 40 + kp] = f2bf(x.w);
            }
        }
        __syncthreads();
        if (kv0 > q0w + 15) continue;
        f32x4 st0 = (f32x4){0.f,0.f,0.f,0.f}, st1 = st0;
#pragma unroll
        for (int db = 0; db < 4; ++db) {
            const int swz = (m & 7) << 4;
            bf16x8 kf0 = *(const bf16x8*)(sK + (m      ) * 256 + ((db * 64 + g * 16) ^ swz));
            bf16x8 kf1 = *(const bf16x8*)(sK + (m + 16 ) * 256 + ((db * 64 + g * 16) ^ swz));
            st0 = __builtin_amdgcn_mfma_f32_16x16x32_bf16(kf0, qf[db], st0, 0, 0, 0);
            st1 = __builtin_amdgcn_mfma_f32_16x16x32_bf16(kf1, qf[db], st1, 0, 0, 0);
        }
        float p[8];
        float tm = -1e30f;
#pragma unroll
        for (int jj = 0; jj < 4; ++jj) {
            int kva = kv0 + g * 4 + jj;
            float s0 = (kva       <= q_abs) ? st0[jj] : -1e30f;
            float s1 = (kva + 16  <= q_abs) ? st1[jj] : -1e30f;
            p[jj]     = s0;
            p[4 + jj] = s1;
            tm = fmaxf(tm, fmaxf(s0, s1));
        }
        tm = fmaxf(tm, __shfl_xor(tm, 16));
        tm = fmaxf(tm, __shfl_xor(tm, 32));
        const float m_new = fmaxf(m_run, tm);
        const float corr  = __expf(m_run - m_new);
        float ls = 0.f;
#pragma unroll
        for (int i = 0; i < 8; ++i) { float e = __expf(p[i] - m_new); p[i] = e; ls += e; }
        ls += __shfl_xor(ls, 16);
        ls += __shfl_xor(ls, 32);
        lsum  = lsum * corr + ls;
        m_run = m_new;
        float cj[4];
#pragma unroll
        for (int jj = 0; jj < 4; ++jj) cj[jj] = __shfl(corr, g * 4 + jj);
#pragma unroll
        for (int i = 0; i < 8; ++i)
#pragma unroll
            for (int jj = 0; jj < 4; ++jj) oacc[i][jj] *= cj[jj];
        bf16x8 pa;
#pragma unroll
        for (int i = 0; i < 8; ++i) pa[i] = (short)f2bf(p[i]);
#pragma unroll
        for (int db8 = 0; db8 < 8; ++db8) {
            bf16x8 vf = *(const bf16x8*)((const unsigned char*)sV +
                          (((db8 * 16 + m) * 40 + g * 8) * 2));
            oacc[db8] = __builtin_amdgcn_mfma_f32_16x16x32_bf16(pa, vf, oacc[db8], 0, 0, 0);
        }
    }
    float rs[4];
    const float rinv = 1.0f / lsum;
#pragma unroll
    for (int jj = 0; jj < 4; ++jj) rs[jj] = __shfl(rinv, g * 4 + jj);
#pragma unroll
    for (int db8 = 0; db8 < 8; ++db8) {
#pragma unroll
        for (int jj = 0; jj < 4; ++jj) {
            const int qr = q0w + g * 4 + jj;
            Og[(size_t)((b * S_ + qr) * H_ + h) * D_ + db8 * 16 + m] = oacc[db8][jj] * rs[jj];
        }
    }
}

extern "C" void kernel_launch(void* const* d_in, const int* in_sizes, int n_in,
                              void* d_out, int out_size, void* d_ws, size_t ws_size,
                              hipStream_t stream) {
    const float* q = (const float*)d_in[0];
    const float* k = (const float*)d_in[1];
    const float* v = (const float*)d_in[2];
    float* o = (float*)d_out;

    const size_t KB_BYTES = (size_t)B_ * HKV_ * S_ * 256;             // 8 MiB
    const size_t VB_BYTES = (size_t)B_ * HKV_ * 32 * 128 * 80 * 2;    // 10 MiB

    if (ws_size >= KB_BYTES + VB_BYTES) {
        unsigned char*  Kb = (unsigned char*)d_ws;
        unsigned short* Vb = (unsigned short*)((unsigned char*)d_ws + KB_BYTES);
        prep_k<<<2048, 256, 0, stream>>>(k, Kb);
        prep_v<<<2048, 256, 0, stream>>>(v, Vb);
        fattn4<<<512, 256, 0, stream>>>(q, Kb, (const unsigned char*)Vb, o);
    } else {
        const int blocks = B_ * H_ * (S_ / QBLK);    // 2048
        fattn_fallback<<<blocks, 256, 0, stream>>>(q, k, v, o);
    }
}

// Round 18
// 106.547 us; speedup vs baseline: 1.0139x; 1.0139x over previous
//
#include <hip/hip_runtime.h>
#include <hip/hip_bf16.h>

typedef short bf16x8 __attribute__((ext_vector_type(8)));
typedef float f32x4  __attribute__((ext_vector_type(4)));

#define B_    2
#define S_    2048
#define H_    32
#define HKV_  8
#define D_    128
#define QBLK  64      // fallback kernel's q-block
#define QBLK2 128     // main kernel's q-block (32 q/wave)
#define KVB   64      // main kernel's kv-tile
// head_dim^-0.5 * log2(e): scores come out in log2 units -> use exp2
#define SCALE 0.1275431741f

static __device__ inline float exp2_fast(float x) {
    return __builtin_amdgcn_exp2f(x);   // v_exp_f32: D = 2^S0
}

static __device__ inline unsigned short f2bf(float f) {
    unsigned u = __builtin_bit_cast(unsigned, f);
    u += 0x7fffu + ((u >> 16) & 1u);   // round-to-nearest-even
    return (unsigned short)(u >> 16);
}
static __device__ inline unsigned pk2(float a, float b) {
    return (unsigned)f2bf(a) | ((unsigned)f2bf(b) << 16);
}
static __device__ inline short cvt_bf(float f) {
    __hip_bfloat16 h = __float2bfloat16(f);
    return __builtin_bit_cast(short, h);
}
static __device__ inline void gload16(const unsigned char* g, unsigned char* l) {
    __builtin_amdgcn_global_load_lds(
        (const __attribute__((address_space(1))) void*)g,
        (__attribute__((address_space(3))) void*)l, 16, 0, 0);
}

// ---------------- pre-pass: K -> bf16 pre-swizzled LDS image ----------------
__global__ __launch_bounds__(256) void prep_k(const float* __restrict__ Kg,
                                              unsigned char* __restrict__ Kb) {
    const int s   = blockIdx.x * 256 + threadIdx.x;     // 524288 16B-slots
    const int seg = s & 15;
    const int kv  = (s >> 4) & (S_ - 1);
    const int bhk = s >> 15;
    const int hk  = bhk & (HKV_ - 1);
    const int b   = bhk >> 3;
    const float* src = Kg + ((size_t)(b * S_ + kv) * HKV_ + hk) * D_ + seg * 8;
    float4 x0 = *(const float4*)(src);
    float4 x1 = *(const float4*)(src + 4);
    uint4 u = { pk2(x0.x, x0.y), pk2(x0.z, x0.w), pk2(x1.x, x1.y), pk2(x1.z, x1.w) };
    *(uint4*)(Kb + ((size_t)(b * HKV_ + hk) * S_ + kv) * 256 + ((seg * 16) ^ ((kv & 7) << 4))) = u;
}

// ---- pre-pass: V -> bf16 transposed+permuted tile image (64kv, 128x80) ----
// Vb[(b*HKV+hk)*32 + tile]: 128 x 80-short image (cols 64..79 pad).
// col = chunk*32 + kp (chunk = kv32-block); kp->kv perm within chunk:
// kv = chunk*32 + ((kp>>2)&1)*16 + (kp>>3)*4 + (kp&3)
__global__ __launch_bounds__(256) void prep_v(const float* __restrict__ Vg,
                                              unsigned short* __restrict__ Vb) {
    const int blk     = blockIdx.x;       // B*HKV*32*4 = 2048
    const int quarter = blk & 3;
    const int tile    = (blk >> 2) & 31;
    const int hk      = (blk >> 7) & (HKV_ - 1);
    const int b       = blk >> 10;
    const int t       = threadIdx.x;
    const int kp0     = (t & 7) * 8;                 // 0..56
    const int d       = (t >> 3) + quarter * 32;     // 0..127
    const int kv0     = tile * KVB;
    unsigned short tmp[8];
#pragma unroll
    for (int j = 0; j < 8; ++j) {
        const int kp    = kp0 + j;
        const int chunk = kp >> 5;
        const int wi    = kp & 31;
        const int kv    = chunk * 32 + (((wi >> 2) & 1) << 4) + ((wi >> 3) << 2) + (wi & 3);
        tmp[j] = f2bf(Vg[((size_t)(b * S_ + kv0 + kv) * HKV_ + hk) * D_ + d]);
    }
    unsigned short* dst = Vb + ((size_t)(b * HKV_ + hk) * 32 + tile) * (128 * 80) + d * 80 + kp0;
    *(uint4*)dst = *(uint4*)tmp;
}

// ------------------------------ main kernel --------------------------------
// 512 uniform blocks: block (pair,hb) runs two sequential kv-sweeps:
// job0 = q-tile (15-pair), job1 = q-tile pair -> 34 staged 64-kv tiles each.
// 2 blocks/CU (72KB LDS), 8 waves/CU sustained, single-barrier pipeline.
__global__ __launch_bounds__(256, 2) void fattn4(
        const float* __restrict__ Qg, const unsigned char* __restrict__ Kb,
        const unsigned char* __restrict__ Vb, float* __restrict__ Og) {
    // per buffer: K 16384B (64x256 swizzled) + V 20480B (128x80 shorts)
    __shared__ __align__(16) unsigned char lds[2 * 36864];

    const int tid  = threadIdx.x;
    const int lane = tid & 63;
    const int w    = tid >> 6;
    const int m    = lane & 15;
    const int g    = lane >> 4;
    const int lane16 = lane * 16;
    const int sw   = (m & 7) << 4;

    const int bid  = blockIdx.x;          // 512 = 8 pairs x 64 (b,h)
    const int pair = bid >> 6;            // 0..7
    const int hb   = bid & 63;
    const int h    = hb & (H_ - 1);
    const int b    = hb >> 5;
    const int hk   = h >> 2;

    const unsigned char* KbH = Kb + (size_t)(b * HKV_ + hk) * S_ * 256;
    const unsigned char* VbH = Vb + (size_t)(b * HKV_ + hk) * 32 * 20480;
    const float* QgH = Qg + (size_t)(b * S_ * H_ + h) * D_;

#define STAGE(kt, cbuf) do {                                                  \
        const unsigned char* KbT = KbH + (size_t)(kt) * 16384;                \
        const unsigned char* VbT = VbH + (size_t)(kt) * 20480;                \
        unsigned char* dK = lds + (cbuf) * 36864;                             \
        unsigned char* dV = dK + 16384;                                       \
        gload16(KbT + (w * 4 + 0) * 1024 + lane16, dK + (w * 4 + 0) * 1024);  \
        gload16(KbT + (w * 4 + 1) * 1024 + lane16, dK + (w * 4 + 1) * 1024);  \
        gload16(KbT + (w * 4 + 2) * 1024 + lane16, dK + (w * 4 + 2) * 1024);  \
        gload16(KbT + (w * 4 + 3) * 1024 + lane16, dK + (w * 4 + 3) * 1024);  \
        gload16(VbT + (w * 5 + 0) * 1024 + lane16, dV + (w * 5 + 0) * 1024);  \
        gload16(VbT + (w * 5 + 1) * 1024 + lane16, dV + (w * 5 + 1) * 1024);  \
        gload16(VbT + (w * 5 + 2) * 1024 + lane16, dV + (w * 5 + 2) * 1024);  \
        gload16(VbT + (w * 5 + 3) * 1024 + lane16, dV + (w * 5 + 3) * 1024);  \
        gload16(VbT + (w * 5 + 4) * 1024 + lane16, dV + (w * 5 + 4) * 1024);  \
    } while (0)

    for (int job = 0; job < 2; ++job) {
        const int qt    = (job == 0) ? (15 - pair) : pair;
        const int qB    = qt * QBLK2;
        const int q0w   = qB + w * 32;
        const int qA    = q0w + m;
        const int qgate = q0w + 31;

        // ---- Q fragments, pre-scaled by SCALE (includes log2e) ----
        bf16x8 qfA[4], qfB[4];
        {
            const float* qrowA = QgH + (size_t)qA * H_ * D_;
            const float* qrowB = qrowA + (size_t)16 * H_ * D_;
#pragma unroll
            for (int db = 0; db < 4; ++db) {
                const float* pA = qrowA + db * 32 + g * 8;
                const float* pB = qrowB + db * 32 + g * 8;
                float4 a0 = *(const float4*)(pA);
                float4 a1 = *(const float4*)(pA + 4);
                float4 b0 = *(const float4*)(pB);
                float4 b1 = *(const float4*)(pB + 4);
                bf16x8 qa, qb;
                qa[0] = cvt_bf(a0.x * SCALE); qa[1] = cvt_bf(a0.y * SCALE);
                qa[2] = cvt_bf(a0.z * SCALE); qa[3] = cvt_bf(a0.w * SCALE);
                qa[4] = cvt_bf(a1.x * SCALE); qa[5] = cvt_bf(a1.y * SCALE);
                qa[6] = cvt_bf(a1.z * SCALE); qa[7] = cvt_bf(a1.w * SCALE);
                qb[0] = cvt_bf(b0.x * SCALE); qb[1] = cvt_bf(b0.y * SCALE);
                qb[2] = cvt_bf(b0.z * SCALE); qb[3] = cvt_bf(b0.w * SCALE);
                qb[4] = cvt_bf(b1.x * SCALE); qb[5] = cvt_bf(b1.y * SCALE);
                qb[6] = cvt_bf(b1.z * SCALE); qb[7] = cvt_bf(b1.w * SCALE);
                qfA[db] = qa; qfB[db] = qb;
            }
        }

        f32x4 oaccA[8], oaccB[8];
#pragma unroll
        for (int i = 0; i < 8; ++i) {
            oaccA[i] = (f32x4){0.f, 0.f, 0.f, 0.f};
            oaccB[i] = (f32x4){0.f, 0.f, 0.f, 0.f};
        }
        float m_run = 4.0f, lsumA = 0.f, lsumB = 0.f;

        const int nt = 2 * (qt + 1);
        int cur = 0;
        STAGE(0, 0);
        asm volatile("s_waitcnt vmcnt(0)" ::: "memory");
        __builtin_amdgcn_s_barrier();

        for (int t = 0; t < nt; ++t) {
            const int kv0 = t * KVB;
            if (t + 1 < nt) STAGE(t + 1, cur ^ 1);   // overlaps compute below

            if (kv0 <= qgate) {
                const unsigned char* cK = lds + cur * 36864;
                const unsigned char* cV = cK + 16384;

                // ---- S^T = K · Q^T, C pre-loaded with -m_run ----
                const f32x4 cinit = (f32x4){-m_run, -m_run, -m_run, -m_run};
                f32x4 sA[4], sB[4];
#pragma unroll
                for (int s = 0; s < 4; ++s) { sA[s] = cinit; sB[s] = cinit; }
                __builtin_amdgcn_s_setprio(1);
#pragma unroll
                for (int db = 0; db < 4; ++db) {
                    const int co = (db * 64 + g * 16) ^ sw;
#pragma unroll
                    for (int s = 0; s < 4; ++s) {
                        bf16x8 kf = *(const bf16x8*)(cK + (m + 16 * s) * 256 + co);
                        sA[s] = __builtin_amdgcn_mfma_f32_16x16x32_bf16(kf, qfA[db], sA[s], 0, 0, 0);
                        sB[s] = __builtin_amdgcn_mfma_f32_16x16x32_bf16(kf, qfB[db], sB[s], 0, 0, 0);
                    }
                }
                __builtin_amdgcn_s_setprio(0);

                // ---- causal mask in place (diagonal tile only) ----
                if (kv0 + (KVB - 1) > q0w) {
                    const int qBrow = qA + 16;
#pragma unroll
                    for (int s = 0; s < 4; ++s)
#pragma unroll
                        for (int jj = 0; jj < 4; ++jj) {
                            const int kva = kv0 + 16 * s + g * 4 + jj;
                            if (kva > qA)    sA[s][jj] = -1e30f;
                            if (kva > qBrow) sB[s][jj] = -1e30f;
                        }
                }

                // per-lane overflow guard on shifted scores; fires ~never
                float pmax = -1e30f;
#pragma unroll
                for (int s = 0; s < 4; ++s)
#pragma unroll
                    for (int jj = 0; jj < 4; ++jj)
                        pmax = fmaxf(pmax, fmaxf(sA[s][jj], sB[s][jj]));
                if (__any(pmax > 12.0f)) {
                    float dm = fmaxf(pmax, __shfl_xor(pmax, 16));
                    dm = fmaxf(dm, __shfl_xor(dm, 32));
                    dm = fmaxf(dm, 0.0f);
                    const float corr = exp2_fast(-dm);
                    lsumA *= corr; lsumB *= corr;
                    float cj[4];
#pragma unroll
                    for (int jj = 0; jj < 4; ++jj) cj[jj] = __shfl(corr, g * 4 + jj);
#pragma unroll
                    for (int i = 0; i < 8; ++i)
#pragma unroll
                        for (int jj = 0; jj < 4; ++jj) {
                            oaccA[i][jj] *= cj[jj];
                            oaccB[i][jj] *= cj[jj];
                        }
                    m_run += dm;
#pragma unroll
                    for (int s = 0; s < 4; ++s)
#pragma unroll
                        for (int jj = 0; jj < 4; ++jj) {
                            sA[s][jj] -= dm; sB[s][jj] -= dm;
                        }
                }

                // ---- exp2 in place, lsum, cvt -> P fragments ----
#pragma unroll
                for (int s = 0; s < 4; ++s)
#pragma unroll
                    for (int jj = 0; jj < 4; ++jj) {
                        sA[s][jj] = exp2_fast(sA[s][jj]);
                        sB[s][jj] = exp2_fast(sB[s][jj]);
                    }
#pragma unroll
                for (int s = 0; s < 4; ++s) {
                    lsumA += (sA[s][0] + sA[s][1]) + (sA[s][2] + sA[s][3]);
                    lsumB += (sB[s][0] + sB[s][1]) + (sB[s][2] + sB[s][3]);
                }

                bf16x8 paA0, paA1, paB0, paB1;
#pragma unroll
                for (int jj = 0; jj < 4; ++jj) {
                    paA0[jj] = cvt_bf(sA[0][jj]); paA0[4 + jj] = cvt_bf(sA[1][jj]);
                    paA1[jj] = cvt_bf(sA[2][jj]); paA1[4 + jj] = cvt_bf(sA[3][jj]);
                    paB0[jj] = cvt_bf(sB[0][jj]); paB0[4 + jj] = cvt_bf(sB[1][jj]);
                    paB1[jj] = cvt_bf(sB[2][jj]); paB1[4 + jj] = cvt_bf(sB[3][jj]);
                }

                // ---- PV: 2 k-steps of 32 kv (chunk 0: cols 0-31, chunk 1: 32-63) ----
                __builtin_amdgcn_s_setprio(1);
#pragma unroll
                for (int db8 = 0; db8 < 8; ++db8) {
                    const unsigned char* vrow = cV + (db8 * 16 + m) * 160 + g * 16;
                    bf16x8 vf0 = *(const bf16x8*)(vrow);
                    bf16x8 vf1 = *(const bf16x8*)(vrow + 64);
                    oaccA[db8] = __builtin_amdgcn_mfma_f32_16x16x32_bf16(paA0, vf0, oaccA[db8], 0, 0, 0);
                    oaccB[db8] = __builtin_amdgcn_mfma_f32_16x16x32_bf16(paB0, vf0, oaccB[db8], 0, 0, 0);
                    oaccA[db8] = __builtin_amdgcn_mfma_f32_16x16x32_bf16(paA1, vf1, oaccA[db8], 0, 0, 0);
                    oaccB[db8] = __builtin_amdgcn_mfma_f32_16x16x32_bf16(paB1, vf1, oaccB[db8], 0, 0, 0);
                }
                __builtin_amdgcn_s_setprio(0);
            }

            // drain this iter's prefetch (hidden under compute), single barrier
            asm volatile("s_waitcnt vmcnt(0)" ::: "memory");
            __builtin_amdgcn_s_barrier();
            cur ^= 1;
        }

        // ---- epilogue: deferred l reductions + O write for this job ----
        lsumA += __shfl_xor(lsumA, 16); lsumA += __shfl_xor(lsumA, 32);
        lsumB += __shfl_xor(lsumB, 16); lsumB += __shfl_xor(lsumB, 32);
        const float rA = 1.0f / lsumA, rB = 1.0f / lsumB;
        float rsA[4], rsB[4];
#pragma unroll
        for (int jj = 0; jj < 4; ++jj) {
            rsA[jj] = __shfl(rA, g * 4 + jj);
            rsB[jj] = __shfl(rB, g * 4 + jj);
        }
#pragma unroll
        for (int db8 = 0; db8 < 8; ++db8) {
#pragma unroll
            for (int jj = 0; jj < 4; ++jj) {
                const int qrA = q0w + g * 4 + jj;
                Og[(size_t)((b * S_ + qrA) * H_ + h) * D_ + db8 * 16 + m]
                    = oaccA[db8][jj] * rsA[jj];
                Og[(size_t)((b * S_ + qrA + 16) * H_ + h) * D_ + db8 * 16 + m]
                    = oaccB[db8][jj] * rsB[jj];
            }
        }
    }
#undef STAGE
}

// ------------------------- fallback (round-0 kernel) ------------------------
__global__ __launch_bounds__(256) void fattn_fallback(
        const float* __restrict__ Qg, const float* __restrict__ Kg,
        const float* __restrict__ Vg, float* __restrict__ Og) {
    __shared__ __align__(16) unsigned char  sK[32 * 256];
    __shared__ __align__(16) unsigned short sV[128 * 40];
    const int tid  = threadIdx.x;
    const int lane = tid & 63;
    const int w    = tid >> 6;
    const int m    = lane & 15;
    const int g    = lane >> 4;
    const int SQ = S_ / QBLK;
    const int bid = blockIdx.x;
    const int qt  = bid % SQ;
    const int h   = (bid / SQ) % H_;
    const int b   = bid / (SQ * H_);
    const int hk  = h >> 2;
    const int qB    = qt * QBLK;
    const int q0w   = qB + w * 16;
    const int q_abs = q0w + m;
    const float SC = 0.08838834764831845f;
    bf16x8 qf[4];
    {
        const float* qrow = Qg + (size_t)((b * S_ + q_abs) * H_ + h) * D_;
#pragma unroll
        for (int db = 0; db < 4; ++db) {
            const float* p = qrow + db * 32 + g * 8;
            float4 a = *(const float4*)(p);
            float4 c = *(const float4*)(p + 4);
            bf16x8 q8;
            q8[0] = (short)f2bf(a.x * SC); q8[1] = (short)f2bf(a.y * SC);
            q8[2] = (short)f2bf(a.z * SC); q8[3] = (short)f2bf(a.w * SC);
            q8[4] = (short)f2bf(c.x * SC); q8[5] = (short)f2bf(c.y * SC);
            q8[6] = (short)f2bf(c.z * SC); q8[7] = (short)f2bf(c.w * SC);
            qf[db] = q8;
        }
    }
    f32x4 oacc[8];
#pragma unroll
    for (int i = 0; i < 8; ++i) oacc[i] = (f32x4){0.f, 0.f, 0.f, 0.f};
    float m_run = -1e30f, lsum = 0.f;
    const int nt = (qB + QBLK) / 32;
    for (int t = 0; t < nt; ++t) {
        const int kv0 = t * 32;
        __syncthreads();
        {
            const int r = tid >> 3, seg = tid & 7;
            const float* src = Kg + (size_t)((b * S_ + kv0 + r) * HKV_ + hk) * D_ + seg * 16;
            float4 x0 = *(const float4*)(src + 0);
            float4 x1 = *(const float4*)(src + 4);
            float4 x2 = *(const float4*)(src + 8);
            float4 x3 = *(const float4*)(src + 12);
            uint4 u0 = { pk2(x0.x,x0.y), pk2(x0.z,x0.w), pk2(x1.x,x1.y), pk2(x1.z,x1.w) };
            uint4 u1 = { pk2(x2.x,x2.y), pk2(x2.z,x2.w), pk2(x3.x,x3.y), pk2(x3.z,x3.w) };
            const int colb = seg * 32;
            const int swz  = (r & 7) << 4;
            *(uint4*)(sK + r * 256 + ((colb     ) ^ swz)) = u0;
            *(uint4*)(sK + r * 256 + ((colb + 16) ^ swz)) = u1;
        }
        {
            const int kv = tid & 31, d0 = (tid >> 5) * 16;
            const int kp = (((kv & 15) >> 2) << 3) + ((kv >> 4) << 2) + (kv & 3);
            const float* src = Vg + (size_t)((b * S_ + kv0 + kv) * HKV_ + hk) * D_ + d0;
#pragma unroll
            for (int i = 0; i < 4; ++i) {
                float4 x = *(const float4*)(src + i * 4);
                const int d = d0 + i * 4;
                sV[(d + 0) * 40 + kp] = f2bf(x.x);
                sV[(d + 1) * 40 + kp] = f2bf(x.y);
                sV[(d + 2) * 40 + kp] = f2bf(x.z);
                sV[(d + 3) * 40 + kp] = f2bf(x.w);
            }
        }
        __syncthreads();
        if (kv0 > q0w + 15) continue;
        f32x4 st0 = (f32x4){0.f,0.f,0.f,0.f}, st1 = st0;
#pragma unroll
        for (int db = 0; db < 4; ++db) {
            const int swz = (m & 7) << 4;
            bf16x8 kf0 = *(const bf16x8*)(sK + (m      ) * 256 + ((db * 64 + g * 16) ^ swz));
            bf16x8 kf1 = *(const bf16x8*)(sK + (m + 16 ) * 256 + ((db * 64 + g * 16) ^ swz));
            st0 = __builtin_amdgcn_mfma_f32_16x16x32_bf16(kf0, qf[db], st0, 0, 0, 0);
            st1 = __builtin_amdgcn_mfma_f32_16x16x32_bf16(kf1, qf[db], st1, 0, 0, 0);
        }
        float p[8];
        float tm = -1e30f;
#pragma unroll
        for (int jj = 0; jj < 4; ++jj) {
            int kva = kv0 + g * 4 + jj;
            float s0 = (kva       <= q_abs) ? st0[jj] : -1e30f;
            float s1 = (kva + 16  <= q_abs) ? st1[jj] : -1e30f;
            p[jj]     = s0;
            p[4 + jj] = s1;
            tm = fmaxf(tm, fmaxf(s0, s1));
        }
        tm = fmaxf(tm, __shfl_xor(tm, 16));
        tm = fmaxf(tm, __shfl_xor(tm, 32));
        const float m_new = fmaxf(m_run, tm);
        const float corr  = __expf(m_run - m_new);
        float ls = 0.f;
#pragma unroll
        for (int i = 0; i < 8; ++i) { float e = __expf(p[i] - m_new); p[i] = e; ls += e; }
        ls += __shfl_xor(ls, 16);
        ls += __shfl_xor(ls, 32);
        lsum  = lsum * corr + ls;
        m_run = m_new;
        float cj[4];
#pragma unroll
        for (int jj = 0; jj < 4; ++jj) cj[jj] = __shfl(corr, g * 4 + jj);
#pragma unroll
        for (int i = 0; i < 8; ++i)
#pragma unroll
            for (int jj = 0; jj < 4; ++jj) oacc[i][jj] *= cj[jj];
        bf16x8 pa;
#pragma unroll
        for (int i = 0; i < 8; ++i) pa[i] = (short)f2bf(p[i]);
#pragma unroll
        for (int db8 = 0; db8 < 8; ++db8) {
            bf16x8 vf = *(const bf16x8*)((const unsigned char*)sV +
                          (((db8 * 16 + m) * 40 + g * 8) * 2));
            oacc[db8] = __builtin_amdgcn_mfma_f32_16x16x32_bf16(pa, vf, oacc[db8], 0, 0, 0);
        }
    }
    float rs[4];
    const float rinv = 1.0f / lsum;
#pragma unroll
    for (int jj = 0; jj < 4; ++jj) rs[jj] = __shfl(rinv, g * 4 + jj);
#pragma unroll
    for (int db8 = 0; db8 < 8; ++db8) {
#pragma unroll
        for (int jj = 0; jj < 4; ++jj) {
            const int qr = q0w + g * 4 + jj;
            Og[(size_t)((b * S_ + qr) * H_ + h) * D_ + db8 * 16 + m] = oacc[db8][jj] * rs[jj];
        }
    }
}

extern "C" void kernel_launch(void* const* d_in, const int* in_sizes, int n_in,
                              void* d_out, int out_size, void* d_ws, size_t ws_size,
                              hipStream_t stream) {
    const float* q = (const float*)d_in[0];
    const float* k = (const float*)d_in[1];
    const float* v = (const float*)d_in[2];
    float* o = (float*)d_out;

    const size_t KB_BYTES = (size_t)B_ * HKV_ * S_ * 256;             // 8 MiB
    const size_t VB_BYTES = (size_t)B_ * HKV_ * 32 * 128 * 80 * 2;    // 10 MiB

    if (ws_size >= KB_BYTES + VB_BYTES) {
        unsigned char*  Kb = (unsigned char*)d_ws;
        unsigned short* Vb = (unsigned short*)((unsigned char*)d_ws + KB_BYTES);
        prep_k<<<2048, 256, 0, stream>>>(k, Kb);
        prep_v<<<2048, 256, 0, stream>>>(v, Vb);
        fattn4<<<512, 256, 0, stream>>>(q, Kb, (const unsigned char*)Vb, o);
    } else {
        const int blocks = B_ * H_ * (S_ / QBLK);    // 2048
        fattn_fallback<<<blocks, 256, 0, stream>>>(q, k, v, o);
    }
}

// Round 19
// 103.745 us; speedup vs baseline: 1.0413x; 1.0270x over previous
//
#include <hip/hip_runtime.h>
#include <hip/hip_bf16.h>

typedef short bf16x8 __attribute__((ext_vector_type(8)));
typedef float f32x4  __attribute__((ext_vector_type(4)));

#define B_    2
#define S_    2048
#define H_    32
#define HKV_  8
#define D_    128
#define QBLK  64      // fallback kernel's q-block
#define QBLK2 128     // main kernel's q-block (32 q/wave)
#define KVB   64      // main kernel's kv-tile
// head_dim^-0.5 * log2(e): scores come out in log2 units -> use exp2
#define SCALE 0.1275431741f

static __device__ inline float exp2_fast(float x) {
    return __builtin_amdgcn_exp2f(x);   // v_exp_f32: D = 2^S0
}

static __device__ inline unsigned short f2bf(float f) {
    unsigned u = __builtin_bit_cast(unsigned, f);
    u += 0x7fffu + ((u >> 16) & 1u);   // round-to-nearest-even
    return (unsigned short)(u >> 16);
}
static __device__ inline unsigned pk2(float a, float b) {
    return (unsigned)f2bf(a) | ((unsigned)f2bf(b) << 16);
}
static __device__ inline short cvt_bf(float f) {
    __hip_bfloat16 h = __float2bfloat16(f);
    return __builtin_bit_cast(short, h);
}
static __device__ inline void gload16(const unsigned char* g, unsigned char* l) {
    __builtin_amdgcn_global_load_lds(
        (const __attribute__((address_space(1))) void*)g,
        (__attribute__((address_space(3))) void*)l, 16, 0, 0);
}

// ---------------- pre-pass: K -> bf16 pre-swizzled LDS image ----------------
__global__ __launch_bounds__(256) void prep_k(const float* __restrict__ Kg,
                                              unsigned char* __restrict__ Kb) {
    const int s   = blockIdx.x * 256 + threadIdx.x;     // 524288 16B-slots
    const int seg = s & 15;
    const int kv  = (s >> 4) & (S_ - 1);
    const int bhk = s >> 15;
    const int hk  = bhk & (HKV_ - 1);
    const int b   = bhk >> 3;
    const float* src = Kg + ((size_t)(b * S_ + kv) * HKV_ + hk) * D_ + seg * 8;
    float4 x0 = *(const float4*)(src);
    float4 x1 = *(const float4*)(src + 4);
    uint4 u = { pk2(x0.x, x0.y), pk2(x0.z, x0.w), pk2(x1.x, x1.y), pk2(x1.z, x1.w) };
    *(uint4*)(Kb + ((size_t)(b * HKV_ + hk) * S_ + kv) * 256 + ((seg * 16) ^ ((kv & 7) << 4))) = u;
}

// ---- pre-pass: V -> bf16 transposed+permuted tile image (64kv, 128x80) ----
// Vb[(b*HKV+hk)*32 + tile]: 128 x 80-short image (cols 64..79 pad).
// col = chunk*32 + kp (chunk = kv32-block); kp->kv perm within chunk:
// kv = chunk*32 + ((kp>>2)&1)*16 + (kp>>3)*4 + (kp&3)
__global__ __launch_bounds__(256) void prep_v(const float* __restrict__ Vg,
                                              unsigned short* __restrict__ Vb) {
    const int blk     = blockIdx.x;       // B*HKV*32*4 = 2048
    const int quarter = blk & 3;
    const int tile    = (blk >> 2) & 31;
    const int hk      = (blk >> 7) & (HKV_ - 1);
    const int b       = blk >> 10;
    const int t       = threadIdx.x;
    const int kp0     = (t & 7) * 8;                 // 0..56
    const int d       = (t >> 3) + quarter * 32;     // 0..127
    const int kv0     = tile * KVB;
    unsigned short tmp[8];
#pragma unroll
    for (int j = 0; j < 8; ++j) {
        const int kp    = kp0 + j;
        const int chunk = kp >> 5;
        const int wi    = kp & 31;
        const int kv    = chunk * 32 + (((wi >> 2) & 1) << 4) + ((wi >> 3) << 2) + (wi & 3);
        tmp[j] = f2bf(Vg[((size_t)(b * S_ + kv0 + kv) * HKV_ + hk) * D_ + d]);
    }
    unsigned short* dst = Vb + ((size_t)(b * HKV_ + hk) * 32 + tile) * (128 * 80) + d * 80 + kp0;
    *(uint4*)dst = *(uint4*)tmp;
}

// ------------------------------ main kernel --------------------------------
// 512 uniform blocks: block (pair,hb) runs two sequential kv-sweeps:
// job0 = q-tile (15-pair), job1 = q-tile pair -> 34 staged 64-kv tiles each.
// 2 blocks/CU (72KB LDS), 8 waves/CU sustained, single-barrier pipeline.
__global__ __launch_bounds__(256, 2) void fattn4(
        const float* __restrict__ Qg, const unsigned char* __restrict__ Kb,
        const unsigned char* __restrict__ Vb, float* __restrict__ Og) {
    // per buffer: K 16384B (64x256 swizzled) + V 20480B (128x80 shorts)
    __shared__ __align__(16) unsigned char lds[2 * 36864];

    const int tid  = threadIdx.x;
    const int lane = tid & 63;
    const int w    = tid >> 6;
    const int m    = lane & 15;
    const int g    = lane >> 4;
    const int lane16 = lane * 16;
    const int sw   = (m & 7) << 4;

    const int bid  = blockIdx.x;          // 512 = 8 pairs x 64 (b,h)
    const int pair = bid >> 6;            // 0..7
    const int hb   = bid & 63;
    const int h    = hb & (H_ - 1);
    const int b    = hb >> 5;
    const int hk   = h >> 2;

    const unsigned char* KbH = Kb + (size_t)(b * HKV_ + hk) * S_ * 256;
    const unsigned char* VbH = Vb + (size_t)(b * HKV_ + hk) * 32 * 20480;
    const float* QgH = Qg + (size_t)(b * S_ * H_ + h) * D_;

#define STAGE(kt, cbuf) do {                                                  \
        const unsigned char* KbT = KbH + (size_t)(kt) * 16384;                \
        const unsigned char* VbT = VbH + (size_t)(kt) * 20480;                \
        unsigned char* dK = lds + (cbuf) * 36864;                             \
        unsigned char* dV = dK + 16384;                                       \
        gload16(KbT + (w * 4 + 0) * 1024 + lane16, dK + (w * 4 + 0) * 1024);  \
        gload16(KbT + (w * 4 + 1) * 1024 + lane16, dK + (w * 4 + 1) * 1024);  \
        gload16(KbT + (w * 4 + 2) * 1024 + lane16, dK + (w * 4 + 2) * 1024);  \
        gload16(KbT + (w * 4 + 3) * 1024 + lane16, dK + (w * 4 + 3) * 1024);  \
        gload16(VbT + (w * 5 + 0) * 1024 + lane16, dV + (w * 5 + 0) * 1024);  \
        gload16(VbT + (w * 5 + 1) * 1024 + lane16, dV + (w * 5 + 1) * 1024);  \
        gload16(VbT + (w * 5 + 2) * 1024 + lane16, dV + (w * 5 + 2) * 1024);  \
        gload16(VbT + (w * 5 + 3) * 1024 + lane16, dV + (w * 5 + 3) * 1024);  \
        gload16(VbT + (w * 5 + 4) * 1024 + lane16, dV + (w * 5 + 4) * 1024);  \
    } while (0)

    for (int job = 0; job < 2; ++job) {
        const int qt    = (job == 0) ? (15 - pair) : pair;
        const int qB    = qt * QBLK2;
        const int q0w   = qB + w * 32;
        const int qA    = q0w + m;
        const int qgate = q0w + 31;

        // ---- Q fragments, pre-scaled by SCALE (includes log2e) ----
        bf16x8 qfA[4], qfB[4];
        {
            const float* qrowA = QgH + (size_t)qA * H_ * D_;
            const float* qrowB = qrowA + (size_t)16 * H_ * D_;
#pragma unroll
            for (int db = 0; db < 4; ++db) {
                const float* pA = qrowA + db * 32 + g * 8;
                const float* pB = qrowB + db * 32 + g * 8;
                float4 a0 = *(const float4*)(pA);
                float4 a1 = *(const float4*)(pA + 4);
                float4 b0 = *(const float4*)(pB);
                float4 b1 = *(const float4*)(pB + 4);
                bf16x8 qa, qb;
                qa[0] = cvt_bf(a0.x * SCALE); qa[1] = cvt_bf(a0.y * SCALE);
                qa[2] = cvt_bf(a0.z * SCALE); qa[3] = cvt_bf(a0.w * SCALE);
                qa[4] = cvt_bf(a1.x * SCALE); qa[5] = cvt_bf(a1.y * SCALE);
                qa[6] = cvt_bf(a1.z * SCALE); qa[7] = cvt_bf(a1.w * SCALE);
                qb[0] = cvt_bf(b0.x * SCALE); qb[1] = cvt_bf(b0.y * SCALE);
                qb[2] = cvt_bf(b0.z * SCALE); qb[3] = cvt_bf(b0.w * SCALE);
                qb[4] = cvt_bf(b1.x * SCALE); qb[5] = cvt_bf(b1.y * SCALE);
                qb[6] = cvt_bf(b1.z * SCALE); qb[7] = cvt_bf(b1.w * SCALE);
                qfA[db] = qa; qfB[db] = qb;
            }
        }

        f32x4 oaccA[8], oaccB[8];
#pragma unroll
        for (int i = 0; i < 8; ++i) {
            oaccA[i] = (f32x4){0.f, 0.f, 0.f, 0.f};
            oaccB[i] = (f32x4){0.f, 0.f, 0.f, 0.f};
        }
        float m_run = 4.0f, lsumA = 0.f, lsumB = 0.f;

        const int nt = 2 * (qt + 1);
        int cur = 0;
        STAGE(0, 0);
        asm volatile("s_waitcnt vmcnt(0)" ::: "memory");
        __builtin_amdgcn_s_barrier();

        for (int t = 0; t < nt; ++t) {
            const int kv0 = t * KVB;
            if (t + 1 < nt) STAGE(t + 1, cur ^ 1);   // overlaps compute below

            if (kv0 <= qgate) {
                const unsigned char* cK = lds + cur * 36864;
                const unsigned char* cV = cK + 16384;

                // ---- S^T = K · Q^T, C pre-loaded with -m_run ----
                const f32x4 cinit = (f32x4){-m_run, -m_run, -m_run, -m_run};
                f32x4 sA[4], sB[4];
#pragma unroll
                for (int s = 0; s < 4; ++s) { sA[s] = cinit; sB[s] = cinit; }
                __builtin_amdgcn_s_setprio(1);
#pragma unroll
                for (int db = 0; db < 4; ++db) {
                    const int co = (db * 64 + g * 16) ^ sw;
#pragma unroll
                    for (int s = 0; s < 4; ++s) {
                        bf16x8 kf = *(const bf16x8*)(cK + (m + 16 * s) * 256 + co);
                        sA[s] = __builtin_amdgcn_mfma_f32_16x16x32_bf16(kf, qfA[db], sA[s], 0, 0, 0);
                        sB[s] = __builtin_amdgcn_mfma_f32_16x16x32_bf16(kf, qfB[db], sB[s], 0, 0, 0);
                    }
                }
                __builtin_amdgcn_s_setprio(0);

                // ---- causal mask in place (diagonal tile only) ----
                if (kv0 + (KVB - 1) > q0w) {
                    const int qBrow = qA + 16;
#pragma unroll
                    for (int s = 0; s < 4; ++s)
#pragma unroll
                        for (int jj = 0; jj < 4; ++jj) {
                            const int kva = kv0 + 16 * s + g * 4 + jj;
                            if (kva > qA)    sA[s][jj] = -1e30f;
                            if (kva > qBrow) sB[s][jj] = -1e30f;
                        }
                }

                // per-lane overflow guard on shifted scores; fires ~never
                float pmax = -1e30f;
#pragma unroll
                for (int s = 0; s < 4; ++s)
#pragma unroll
                    for (int jj = 0; jj < 4; ++jj)
                        pmax = fmaxf(pmax, fmaxf(sA[s][jj], sB[s][jj]));
                if (__any(pmax > 12.0f)) {
                    float dm = fmaxf(pmax, __shfl_xor(pmax, 16));
                    dm = fmaxf(dm, __shfl_xor(dm, 32));
                    dm = fmaxf(dm, 0.0f);
                    const float corr = exp2_fast(-dm);
                    lsumA *= corr; lsumB *= corr;
                    float cj[4];
#pragma unroll
                    for (int jj = 0; jj < 4; ++jj) cj[jj] = __shfl(corr, g * 4 + jj);
#pragma unroll
                    for (int i = 0; i < 8; ++i)
#pragma unroll
                        for (int jj = 0; jj < 4; ++jj) {
                            oaccA[i][jj] *= cj[jj];
                            oaccB[i][jj] *= cj[jj];
                        }
                    m_run += dm;
#pragma unroll
                    for (int s = 0; s < 4; ++s)
#pragma unroll
                        for (int jj = 0; jj < 4; ++jj) {
                            sA[s][jj] -= dm; sB[s][jj] -= dm;
                        }
                }

                // ---- exp2 in place, lsum, cvt -> P fragments ----
#pragma unroll
                for (int s = 0; s < 4; ++s)
#pragma unroll
                    for (int jj = 0; jj < 4; ++jj) {
                        sA[s][jj] = exp2_fast(sA[s][jj]);
                        sB[s][jj] = exp2_fast(sB[s][jj]);
                    }
#pragma unroll
                for (int s = 0; s < 4; ++s) {
                    lsumA += (sA[s][0] + sA[s][1]) + (sA[s][2] + sA[s][3]);
                    lsumB += (sB[s][0] + sB[s][1]) + (sB[s][2] + sB[s][3]);
                }

                bf16x8 paA0, paA1, paB0, paB1;
#pragma unroll
                for (int jj = 0; jj < 4; ++jj) {
                    paA0[jj] = cvt_bf(sA[0][jj]); paA0[4 + jj] = cvt_bf(sA[1][jj]);
                    paA1[jj] = cvt_bf(sA[2][jj]); paA1[4 + jj] = cvt_bf(sA[3][jj]);
                    paB0[jj] = cvt_bf(sB[0][jj]); paB0[4 + jj] = cvt_bf(sB[1][jj]);
                    paB1[jj] = cvt_bf(sB[2][jj]); paB1[4 + jj] = cvt_bf(sB[3][jj]);
                }

                // ---- PV: 2 k-steps of 32 kv (chunk 0: cols 0-31, chunk 1: 32-63) ----
                __builtin_amdgcn_s_setprio(1);
#pragma unroll
                for (int db8 = 0; db8 < 8; ++db8) {
                    const unsigned char* vrow = cV + (db8 * 16 + m) * 160 + g * 16;
                    bf16x8 vf0 = *(const bf16x8*)(vrow);
                    bf16x8 vf1 = *(const bf16x8*)(vrow + 64);
                    oaccA[db8] = __builtin_amdgcn_mfma_f32_16x16x32_bf16(paA0, vf0, oaccA[db8], 0, 0, 0);
                    oaccB[db8] = __builtin_amdgcn_mfma_f32_16x16x32_bf16(paB0, vf0, oaccB[db8], 0, 0, 0);
                    oaccA[db8] = __builtin_amdgcn_mfma_f32_16x16x32_bf16(paA1, vf1, oaccA[db8], 0, 0, 0);
                    oaccB[db8] = __builtin_amdgcn_mfma_f32_16x16x32_bf16(paB1, vf1, oaccB[db8], 0, 0, 0);
                }
                __builtin_amdgcn_s_setprio(0);
            }

            // drain this iter's prefetch (hidden under compute), single barrier
            asm volatile("s_waitcnt vmcnt(0)" ::: "memory");
            __builtin_amdgcn_s_barrier();
            cur ^= 1;
        }

        // ---- epilogue: deferred l reductions + O write for this job ----
        lsumA += __shfl_xor(lsumA, 16); lsumA += __shfl_xor(lsumA, 32);
        lsumB += __shfl_xor(lsumB, 16); lsumB += __shfl_xor(lsumB, 32);
        const float rA = 1.0f / lsumA, rB = 1.0f / lsumB;
        float rsA[4], rsB[4];
#pragma unroll
        for (int jj = 0; jj < 4; ++jj) {
            rsA[jj] = __shfl(rA, g * 4 + jj);
            rsB[jj] = __shfl(rB, g * 4 + jj);
        }
#pragma unroll
        for (int db8 = 0; db8 < 8; ++db8) {
#pragma unroll
            for (int jj = 0; jj < 4; ++jj) {
                const int qrA = q0w + g * 4 + jj;
                Og[(size_t)((b * S_ + qrA) * H_ + h) * D_ + db8 * 16 + m]
                    = oaccA[db8][jj] * rsA[jj];
                Og[(size_t)((b * S_ + qrA + 16) * H_ + h) * D_ + db8 * 16 + m]
                    = oaccB[db8][jj] * rsB[jj];
            }
        }
    }
#undef STAGE
}

// ------------------------- fallback (round-0 kernel) ------------------------
__global__ __launch_bounds__(256) void fattn_fallback(
        const float* __restrict__ Qg, const float* __restrict__ Kg,
        const float* __restrict__ Vg, float* __restrict__ Og) {
    __shared__ __align__(16) unsigned char  sK[32 * 256];
    __shared__ __align__(16) unsigned short sV[128 * 40];
    const int tid  = threadIdx.x;
    const int lane = tid & 63;
    const int w    = tid >> 6;
    const int m    = lane & 15;
    const int g    = lane >> 4;
    const int SQ = S_ / QBLK;
    const int bid = blockIdx.x;
    const int qt  = bid % SQ;
    const int h   = (bid / SQ) % H_;
    const int b   = bid / (SQ * H_);
    const int hk  = h >> 2;
    const int qB    = qt * QBLK;
    const int q0w   = qB + w * 16;
    const int q_abs = q0w + m;
    const float SC = 0.08838834764831845f;
    bf16x8 qf[4];
    {
        const float* qrow = Qg + (size_t)((b * S_ + q_abs) * H_ + h) * D_;
#pragma unroll
        for (int db = 0; db < 4; ++db) {
            const float* p = qrow + db * 32 + g * 8;
            float4 a = *(const float4*)(p);
            float4 c = *(const float4*)(p + 4);
            bf16x8 q8;
            q8[0] = (short)f2bf(a.x * SC); q8[1] = (short)f2bf(a.y * SC);
            q8[2] = (short)f2bf(a.z * SC); q8[3] = (short)f2bf(a.w * SC);
            q8[4] = (short)f2bf(c.x * SC); q8[5] = (short)f2bf(c.y * SC);
            q8[6] = (short)f2bf(c.z * SC); q8[7] = (short)f2bf(c.w * SC);
            qf[db] = q8;
        }
    }
    f32x4 oacc[8];
#pragma unroll
    for (int i = 0; i < 8; ++i) oacc[i] = (f32x4){0.f, 0.f, 0.f, 0.f};
    float m_run = -1e30f, lsum = 0.f;
    const int nt = (qB + QBLK) / 32;
    for (int t = 0; t < nt; ++t) {
        const int kv0 = t * 32;
        __syncthreads();
        {
            const int r = tid >> 3, seg = tid & 7;
            const float* src = Kg + (size_t)((b * S_ + kv0 + r) * HKV_ + hk) * D_ + seg * 16;
            float4 x0 = *(const float4*)(src + 0);
            float4 x1 = *(const float4*)(src + 4);
            float4 x2 = *(const float4*)(src + 8);
            float4 x3 = *(const float4*)(src + 12);
            uint4 u0 = { pk2(x0.x,x0.y), pk2(x0.z,x0.w), pk2(x1.x,x1.y), pk2(x1.z,x1.w) };
            uint4 u1 = { pk2(x2.x,x2.y), pk2(x2.z,x2.w), pk2(x3.x,x3.y), pk2(x3.z,x3.w) };
            const int colb = seg * 32;
            const int swz  = (r & 7) << 4;
            *(uint4*)(sK + r * 256 + ((colb     ) ^ swz)) = u0;
            *(uint4*)(sK + r * 256 + ((colb + 16) ^ swz)) = u1;
        }
        {
            const int kv = tid & 31, d0 = (tid >> 5) * 16;
            const int kp = (((kv & 15) >> 2) << 3) + ((kv >> 4) << 2) + (kv & 3);
            const float* src = Vg + (size_t)((b * S_ + kv0 + kv) * HKV_ + hk) * D_ + d0;
#pragma unroll
            for (int i = 0; i < 4; ++i) {
                float4 x = *(const float4*)(src + i * 4);
                const int d = d0 + i * 4;
                sV[(d + 0) * 40 + kp] = f2bf(x.x);
                sV[(d + 1) * 40 + kp] = f2bf(x.y);
                sV[(d + 2) * 40 + kp] = f2bf(x.z);
                sV[(d + 3) * 40 + kp] = f2bf(x.w);
            }
        }
        __syncthreads();
        if (kv0 > q0w + 15) continue;
        f32x4 st0 = (f32x4){0.f,0.f,0.f,0.f}, st1 = st0;
#pragma unroll
        for (int db = 0; db < 4; ++db) {
            const int swz = (m & 7) << 4;
            bf16x8 kf0 = *(const bf16x8*)(sK + (m      ) * 256 + ((db * 64 + g * 16) ^ swz));
            bf16x8 kf1 = *(const bf16x8*)(sK + (m + 16 ) * 256 + ((db * 64 + g * 16) ^ swz));
            st0 = __builtin_amdgcn_mfma_f32_16x16x32_bf16(kf0, qf[db], st0, 0, 0, 0);
            st1 = __builtin_amdgcn_mfma_f32_16x16x32_bf16(kf1, qf[db], st1, 0, 0, 0);
        }
        float p[8];
        float tm = -1e30f;
#pragma unroll
        for (int jj = 0; jj < 4; ++jj) {
            int kva = kv0 + g * 4 + jj;
            float s0 = (kva       <= q_abs) ? st0[jj] : -1e30f;
            float s1 = (kva + 16  <= q_abs) ? st1[jj] : -1e30f;
            p[jj]     = s0;
            p[4 + jj] = s1;
            tm = fmaxf(tm, fmaxf(s0, s1));
        }
        tm = fmaxf(tm, __shfl_xor(tm, 16));
        tm = fmaxf(tm, __shfl_xor(tm, 32));
        const float m_new = fmaxf(m_run, tm);
        const float corr  = __expf(m_run - m_new);
        float ls = 0.f;
#pragma unroll
        for (int i = 0; i < 8; ++i) { float e = __expf(p[i] - m_new); p[i] = e; ls += e; }
        ls += __shfl_xor(ls, 16);
        ls += __shfl_xor(ls, 32);
        lsum  = lsum * corr + ls;
        m_run = m_new;
        float cj[4];
#pragma unroll
        for (int jj = 0; jj < 4; ++jj) cj[jj] = __shfl(corr, g * 4 + jj);
#pragma unroll
        for (int i = 0; i < 8; ++i)
#pragma unroll
            for (int jj = 0; jj < 4; ++jj) oacc[i][jj] *= cj[jj];
        bf16x8 pa;
#pragma unroll
        for (int i = 0; i < 8; ++i) pa[i] = (short)f2bf(p[i]);
#pragma unroll
        for (int db8 = 0; db8 < 8; ++db8) {
            bf16x8 vf = *(const bf16x8*)((const unsigned char*)sV +
                          (((db8 * 16 + m) * 40 + g * 8) * 2));
            oacc[db8] = __builtin_amdgcn_mfma_f32_16x16x32_bf16(pa, vf, oacc[db8], 0, 0, 0);
        }
    }
    float rs[4];
    const float rinv = 1.0f / lsum;
#pragma unroll
    for (int jj = 0; jj < 4; ++jj) rs[jj] = __shfl(rinv, g * 4 + jj);
#pragma unroll
    for (int db8 = 0; db8 < 8; ++db8) {
#pragma unroll
        for (int jj = 0; jj < 4; ++jj) {
            const int qr = q0w + g * 4 + jj;
            Og[(size_t)((b * S_ + qr) * H_ + h) * D_ + db8 * 16 + m] = oacc[db8][jj] * rs[jj];
        }
    }
}

extern "C" void kernel_launch(void* const* d_in, const int* in_sizes, int n_in,
                              void* d_out, int out_size, void* d_ws, size_t ws_size,
                              hipStream_t stream) {
    const float* q = (const float*)d_in[0];
    const float* k = (const float*)d_in[1];
    const float* v = (const float*)d_in[2];
    float* o = (float*)d_out;

    const size_t KB_BYTES = (size_t)B_ * HKV_ * S_ * 256;             // 8 MiB
    const size_t VB_BYTES = (size_t)B_ * HKV_ * 32 * 128 * 80 * 2;    // 10 MiB

    if (ws_size >= KB_BYTES + VB_BYTES) {
        unsigned char*  Kb = (unsigned char*)d_ws;
        unsigned short* Vb = (unsigned short*)((unsigned char*)d_ws + KB_BYTES);
        prep_k<<<2048, 256, 0, stream>>>(k, Kb);
        prep_v<<<2048, 256, 0, stream>>>(v, Vb);
        fattn4<<<512, 256, 0, stream>>>(q, Kb, (const unsigned char*)Vb, o);
    } else {
        const int blocks = B_ * H_ * (S_ / QBLK);    // 2048
        fattn_fallback<<<blocks, 256, 0, stream>>>(q, k, v, o);
    }
}

// Round 20
// 101.794 us; speedup vs baseline: 1.0612x; 1.0192x over previous
//
#include <hip/hip_runtime.h>
#include <hip/hip_bf16.h>

typedef short bf16x8 __attribute__((ext_vector_type(8)));
typedef float f32x4  __attribute__((ext_vector_type(4)));

#define B_    2
#define S_    2048
#define H_    32
#define HKV_  8
#define D_    128
#define QBLK  64      // fallback kernel's q-block
#define QBLK2 128     // main kernel's q-block (32 q/wave)
#define KVB   64      // main kernel's kv-tile
// head_dim^-0.5 * log2(e): scores come out in log2 units -> use exp2
#define SCALE 0.1275431741f

static __device__ inline float exp2_fast(float x) {
    return __builtin_amdgcn_exp2f(x);   // v_exp_f32: D = 2^S0
}

static __device__ inline unsigned short f2bf(float f) {
    unsigned u = __builtin_bit_cast(unsigned, f);
    u += 0x7fffu + ((u >> 16) & 1u);   // round-to-nearest-even
    return (unsigned short)(u >> 16);
}
static __device__ inline unsigned pk2(float a, float b) {
    return (unsigned)f2bf(a) | ((unsigned)f2bf(b) << 16);
}
static __device__ inline short cvt_bf(float f) {
    __hip_bfloat16 h = __float2bfloat16(f);
    return __builtin_bit_cast(short, h);
}
static __device__ inline void gload16(const unsigned char* g, unsigned char* l) {
    __builtin_amdgcn_global_load_lds(
        (const __attribute__((address_space(1))) void*)g,
        (__attribute__((address_space(3))) void*)l, 16, 0, 0);
}

// ---------------- pre-pass: K -> bf16 pre-swizzled LDS image ----------------
__global__ __launch_bounds__(256) void prep_k(const float* __restrict__ Kg,
                                              unsigned char* __restrict__ Kb) {
    const int s   = blockIdx.x * 256 + threadIdx.x;     // 524288 16B-slots
    const int seg = s & 15;
    const int kv  = (s >> 4) & (S_ - 1);
    const int bhk = s >> 15;
    const int hk  = bhk & (HKV_ - 1);
    const int b   = bhk >> 3;
    const float* src = Kg + ((size_t)(b * S_ + kv) * HKV_ + hk) * D_ + seg * 8;
    float4 x0 = *(const float4*)(src);
    float4 x1 = *(const float4*)(src + 4);
    uint4 u = { pk2(x0.x, x0.y), pk2(x0.z, x0.w), pk2(x1.x, x1.y), pk2(x1.z, x1.w) };
    *(uint4*)(Kb + ((size_t)(b * HKV_ + hk) * S_ + kv) * 256 + ((seg * 16) ^ ((kv & 7) << 4))) = u;
}

// ---- pre-pass: V -> bf16 transposed+permuted tile image (64kv, 128x80) ----
// Vb[(b*HKV+hk)*32 + tile]: 128 x 80-short image (cols 64..79 pad).
// col = chunk*32 + kp (chunk = kv32-block); kp->kv perm within chunk:
// kv = chunk*32 + ((kp>>2)&1)*16 + (kp>>3)*4 + (kp&3)
__global__ __launch_bounds__(256) void prep_v(const float* __restrict__ Vg,
                                              unsigned short* __restrict__ Vb) {
    const int blk     = blockIdx.x;       // B*HKV*32*4 = 2048
    const int quarter = blk & 3;
    const int tile    = (blk >> 2) & 31;
    const int hk      = (blk >> 7) & (HKV_ - 1);
    const int b       = blk >> 10;
    const int t       = threadIdx.x;
    const int kp0     = (t & 7) * 8;                 // 0..56
    const int d       = (t >> 3) + quarter * 32;     // 0..127
    const int kv0     = tile * KVB;
    unsigned short tmp[8];
#pragma unroll
    for (int j = 0; j < 8; ++j) {
        const int kp    = kp0 + j;
        const int chunk = kp >> 5;
        const int wi    = kp & 31;
        const int kv    = chunk * 32 + (((wi >> 2) & 1) << 4) + ((wi >> 3) << 2) + (wi & 3);
        tmp[j] = f2bf(Vg[((size_t)(b * S_ + kv0 + kv) * HKV_ + hk) * D_ + d]);
    }
    unsigned short* dst = Vb + ((size_t)(b * HKV_ + hk) * 32 + tile) * (128 * 80) + d * 80 + kp0;
    *(uint4*)dst = *(uint4*)tmp;
}

// ------------------------------ main kernel --------------------------------
// 512 uniform blocks: block (pair,hb) runs two sequential kv-sweeps:
// job0 = q-tile (15-pair), job1 = q-tile pair -> 34 staged 64-kv tiles each.
// 2 blocks/CU (72KB LDS), single-barrier pipeline (R12/R19 body).
// R20: single prologue; job1's tile 0 prefetched during job0's last iter
//      (removes the per-job STAGE+drain+barrier bubble).
__global__ __launch_bounds__(256, 2) void fattn4(
        const float* __restrict__ Qg, const unsigned char* __restrict__ Kb,
        const unsigned char* __restrict__ Vb, float* __restrict__ Og) {
    // per buffer: K 16384B (64x256 swizzled) + V 20480B (128x80 shorts)
    __shared__ __align__(16) unsigned char lds[2 * 36864];

    const int tid  = threadIdx.x;
    const int lane = tid & 63;
    const int w    = tid >> 6;
    const int m    = lane & 15;
    const int g    = lane >> 4;
    const int lane16 = lane * 16;
    const int sw   = (m & 7) << 4;

    const int bid  = blockIdx.x;          // 512 = 8 pairs x 64 (b,h)
    const int pair = bid >> 6;            // 0..7
    const int hb   = bid & 63;
    const int h    = hb & (H_ - 1);
    const int b    = hb >> 5;
    const int hk   = h >> 2;

    const unsigned char* KbH = Kb + (size_t)(b * HKV_ + hk) * S_ * 256;
    const unsigned char* VbH = Vb + (size_t)(b * HKV_ + hk) * 32 * 20480;
    const float* QgH = Qg + (size_t)(b * S_ * H_ + h) * D_;

#define STAGE(kt, cbuf) do {                                                  \
        const unsigned char* KbT = KbH + (size_t)(kt) * 16384;                \
        const unsigned char* VbT = VbH + (size_t)(kt) * 20480;                \
        unsigned char* dK = lds + (cbuf) * 36864;                             \
        unsigned char* dV = dK + 16384;                                       \
        gload16(KbT + (w * 4 + 0) * 1024 + lane16, dK + (w * 4 + 0) * 1024);  \
        gload16(KbT + (w * 4 + 1) * 1024 + lane16, dK + (w * 4 + 1) * 1024);  \
        gload16(KbT + (w * 4 + 2) * 1024 + lane16, dK + (w * 4 + 2) * 1024);  \
        gload16(KbT + (w * 4 + 3) * 1024 + lane16, dK + (w * 4 + 3) * 1024);  \
        gload16(VbT + (w * 5 + 0) * 1024 + lane16, dV + (w * 5 + 0) * 1024);  \
        gload16(VbT + (w * 5 + 1) * 1024 + lane16, dV + (w * 5 + 1) * 1024);  \
        gload16(VbT + (w * 5 + 2) * 1024 + lane16, dV + (w * 5 + 2) * 1024);  \
        gload16(VbT + (w * 5 + 3) * 1024 + lane16, dV + (w * 5 + 3) * 1024);  \
        gload16(VbT + (w * 5 + 4) * 1024 + lane16, dV + (w * 5 + 4) * 1024);  \
    } while (0)

    int cur = 0;
    STAGE(0, 0);
    asm volatile("s_waitcnt vmcnt(0)" ::: "memory");
    __builtin_amdgcn_s_barrier();

    for (int job = 0; job < 2; ++job) {
        const int qt    = (job == 0) ? (15 - pair) : pair;
        const int qB    = qt * QBLK2;
        const int q0w   = qB + w * 32;
        const int qA    = q0w + m;
        const int qgate = q0w + 31;

        // ---- Q fragments, pre-scaled by SCALE (includes log2e) ----
        bf16x8 qfA[4], qfB[4];
        {
            const float* qrowA = QgH + (size_t)qA * H_ * D_;
            const float* qrowB = qrowA + (size_t)16 * H_ * D_;
#pragma unroll
            for (int db = 0; db < 4; ++db) {
                const float* pA = qrowA + db * 32 + g * 8;
                const float* pB = qrowB + db * 32 + g * 8;
                float4 a0 = *(const float4*)(pA);
                float4 a1 = *(const float4*)(pA + 4);
                float4 b0 = *(const float4*)(pB);
                float4 b1 = *(const float4*)(pB + 4);
                bf16x8 qa, qb;
                qa[0] = cvt_bf(a0.x * SCALE); qa[1] = cvt_bf(a0.y * SCALE);
                qa[2] = cvt_bf(a0.z * SCALE); qa[3] = cvt_bf(a0.w * SCALE);
                qa[4] = cvt_bf(a1.x * SCALE); qa[5] = cvt_bf(a1.y * SCALE);
                qa[6] = cvt_bf(a1.z * SCALE); qa[7] = cvt_bf(a1.w * SCALE);
                qb[0] = cvt_bf(b0.x * SCALE); qb[1] = cvt_bf(b0.y * SCALE);
                qb[2] = cvt_bf(b0.z * SCALE); qb[3] = cvt_bf(b0.w * SCALE);
                qb[4] = cvt_bf(b1.x * SCALE); qb[5] = cvt_bf(b1.y * SCALE);
                qb[6] = cvt_bf(b1.z * SCALE); qb[7] = cvt_bf(b1.w * SCALE);
                qfA[db] = qa; qfB[db] = qb;
            }
        }

        f32x4 oaccA[8], oaccB[8];
#pragma unroll
        for (int i = 0; i < 8; ++i) {
            oaccA[i] = (f32x4){0.f, 0.f, 0.f, 0.f};
            oaccB[i] = (f32x4){0.f, 0.f, 0.f, 0.f};
        }
        float m_run = 4.0f, lsumA = 0.f, lsumB = 0.f;

        const int nt = 2 * (qt + 1);

        for (int t = 0; t < nt; ++t) {
            const int kv0 = t * KVB;
            if (t + 1 < nt)       STAGE(t + 1, cur ^ 1);   // overlaps compute
            else if (job == 0)    STAGE(0, cur ^ 1);       // prefetch job1 tile 0

            if (kv0 <= qgate) {
                const unsigned char* cK = lds + cur * 36864;
                const unsigned char* cV = cK + 16384;

                // ---- S^T = K · Q^T, C pre-loaded with -m_run ----
                const f32x4 cinit = (f32x4){-m_run, -m_run, -m_run, -m_run};
                f32x4 sA[4], sB[4];
#pragma unroll
                for (int s = 0; s < 4; ++s) { sA[s] = cinit; sB[s] = cinit; }
                __builtin_amdgcn_s_setprio(1);
#pragma unroll
                for (int db = 0; db < 4; ++db) {
                    const int co = (db * 64 + g * 16) ^ sw;
#pragma unroll
                    for (int s = 0; s < 4; ++s) {
                        bf16x8 kf = *(const bf16x8*)(cK + (m + 16 * s) * 256 + co);
                        sA[s] = __builtin_amdgcn_mfma_f32_16x16x32_bf16(kf, qfA[db], sA[s], 0, 0, 0);
                        sB[s] = __builtin_amdgcn_mfma_f32_16x16x32_bf16(kf, qfB[db], sB[s], 0, 0, 0);
                    }
                }
                __builtin_amdgcn_s_setprio(0);

                // ---- causal mask in place (diagonal tile only) ----
                if (kv0 + (KVB - 1) > q0w) {
                    const int qBrow = qA + 16;
#pragma unroll
                    for (int s = 0; s < 4; ++s)
#pragma unroll
                        for (int jj = 0; jj < 4; ++jj) {
                            const int kva = kv0 + 16 * s + g * 4 + jj;
                            if (kva > qA)    sA[s][jj] = -1e30f;
                            if (kva > qBrow) sB[s][jj] = -1e30f;
                        }
                }

                // per-lane overflow guard on shifted scores; fires ~never
                float pmax = -1e30f;
#pragma unroll
                for (int s = 0; s < 4; ++s)
#pragma unroll
                    for (int jj = 0; jj < 4; ++jj)
                        pmax = fmaxf(pmax, fmaxf(sA[s][jj], sB[s][jj]));
                if (__any(pmax > 12.0f)) {
                    float dm = fmaxf(pmax, __shfl_xor(pmax, 16));
                    dm = fmaxf(dm, __shfl_xor(dm, 32));
                    dm = fmaxf(dm, 0.0f);
                    const float corr = exp2_fast(-dm);
                    lsumA *= corr; lsumB *= corr;
                    float cj[4];
#pragma unroll
                    for (int jj = 0; jj < 4; ++jj) cj[jj] = __shfl(corr, g * 4 + jj);
#pragma unroll
                    for (int i = 0; i < 8; ++i)
#pragma unroll
                        for (int jj = 0; jj < 4; ++jj) {
                            oaccA[i][jj] *= cj[jj];
                            oaccB[i][jj] *= cj[jj];
                        }
                    m_run += dm;
#pragma unroll
                    for (int s = 0; s < 4; ++s)
#pragma unroll
                        for (int jj = 0; jj < 4; ++jj) {
                            sA[s][jj] -= dm; sB[s][jj] -= dm;
                        }
                }

                // ---- exp2 in place, lsum, cvt -> P fragments ----
#pragma unroll
                for (int s = 0; s < 4; ++s)
#pragma unroll
                    for (int jj = 0; jj < 4; ++jj) {
                        sA[s][jj] = exp2_fast(sA[s][jj]);
                        sB[s][jj] = exp2_fast(sB[s][jj]);
                    }
#pragma unroll
                for (int s = 0; s < 4; ++s) {
                    lsumA += (sA[s][0] + sA[s][1]) + (sA[s][2] + sA[s][3]);
                    lsumB += (sB[s][0] + sB[s][1]) + (sB[s][2] + sB[s][3]);
                }

                bf16x8 paA0, paA1, paB0, paB1;
#pragma unroll
                for (int jj = 0; jj < 4; ++jj) {
                    paA0[jj] = cvt_bf(sA[0][jj]); paA0[4 + jj] = cvt_bf(sA[1][jj]);
                    paA1[jj] = cvt_bf(sA[2][jj]); paA1[4 + jj] = cvt_bf(sA[3][jj]);
                    paB0[jj] = cvt_bf(sB[0][jj]); paB0[4 + jj] = cvt_bf(sB[1][jj]);
                    paB1[jj] = cvt_bf(sB[2][jj]); paB1[4 + jj] = cvt_bf(sB[3][jj]);
                }

                // ---- PV: 2 k-steps of 32 kv (chunk 0: cols 0-31, chunk 1: 32-63) ----
                __builtin_amdgcn_s_setprio(1);
#pragma unroll
                for (int db8 = 0; db8 < 8; ++db8) {
                    const unsigned char* vrow = cV + (db8 * 16 + m) * 160 + g * 16;
                    bf16x8 vf0 = *(const bf16x8*)(vrow);
                    bf16x8 vf1 = *(const bf16x8*)(vrow + 64);
                    oaccA[db8] = __builtin_amdgcn_mfma_f32_16x16x32_bf16(paA0, vf0, oaccA[db8], 0, 0, 0);
                    oaccB[db8] = __builtin_amdgcn_mfma_f32_16x16x32_bf16(paB0, vf0, oaccB[db8], 0, 0, 0);
                    oaccA[db8] = __builtin_amdgcn_mfma_f32_16x16x32_bf16(paA1, vf1, oaccA[db8], 0, 0, 0);
                    oaccB[db8] = __builtin_amdgcn_mfma_f32_16x16x32_bf16(paB1, vf1, oaccB[db8], 0, 0, 0);
                }
                __builtin_amdgcn_s_setprio(0);
            }

            // drain this iter's prefetch (hidden under compute), single barrier
            asm volatile("s_waitcnt vmcnt(0)" ::: "memory");
            __builtin_amdgcn_s_barrier();
            cur ^= 1;
        }

        // ---- epilogue: deferred l reductions + O write for this job ----
        lsumA += __shfl_xor(lsumA, 16); lsumA += __shfl_xor(lsumA, 32);
        lsumB += __shfl_xor(lsumB, 16); lsumB += __shfl_xor(lsumB, 32);
        const float rA = 1.0f / lsumA, rB = 1.0f / lsumB;
        float rsA[4], rsB[4];
#pragma unroll
        for (int jj = 0; jj < 4; ++jj) {
            rsA[jj] = __shfl(rA, g * 4 + jj);
            rsB[jj] = __shfl(rB, g * 4 + jj);
        }
#pragma unroll
        for (int db8 = 0; db8 < 8; ++db8) {
#pragma unroll
            for (int jj = 0; jj < 4; ++jj) {
                const int qrA = q0w + g * 4 + jj;
                Og[(size_t)((b * S_ + qrA) * H_ + h) * D_ + db8 * 16 + m]
                    = oaccA[db8][jj] * rsA[jj];
                Og[(size_t)((b * S_ + qrA + 16) * H_ + h) * D_ + db8 * 16 + m]
                    = oaccB[db8][jj] * rsB[jj];
            }
        }
        // job1's tile 0 already staged & drained; buffers safe to reuse.
    }
#undef STAGE
}

// ------------------------- fallback (round-0 kernel) ------------------------
__global__ __launch_bounds__(256) void fattn_fallback(
        const float* __restrict__ Qg, const float* __restrict__ Kg,
        const float* __restrict__ Vg, float* __restrict__ Og) {
    __shared__ __align__(16) unsigned char  sK[32 * 256];
    __shared__ __align__(16) unsigned short sV[128 * 40];
    const int tid  = threadIdx.x;
    const int lane = tid & 63;
    const int w    = tid >> 6;
    const int m    = lane & 15;
    const int g    = lane >> 4;
    const int SQ = S_ / QBLK;
    const int bid = blockIdx.x;
    const int qt  = bid % SQ;
    const int h   = (bid / SQ) % H_;
    const int b   = bid / (SQ * H_);
    const int hk  = h >> 2;
    const int qB    = qt * QBLK;
    const int q0w   = qB + w * 16;
    const int q_abs = q0w + m;
    const float SC = 0.08838834764831845f;
    bf16x8 qf[4];
    {
        const float* qrow = Qg + (size_t)((b * S_ + q_abs) * H_ + h) * D_;
#pragma unroll
        for (int db = 0; db < 4; ++db) {
            const float* p = qrow + db * 32 + g * 8;
            float4 a = *(const float4*)(p);
            float4 c = *(const float4*)(p + 4);
            bf16x8 q8;
            q8[0] = (short)f2bf(a.x * SC); q8[1] = (short)f2bf(a.y * SC);
            q8[2] = (short)f2bf(a.z * SC); q8[3] = (short)f2bf(a.w * SC);
            q8[4] = (short)f2bf(c.x * SC); q8[5] = (short)f2bf(c.y * SC);
            q8[6] = (short)f2bf(c.z * SC); q8[7] = (short)f2bf(c.w * SC);
            qf[db] = q8;
        }
    }
    f32x4 oacc[8];
#pragma unroll
    for (int i = 0; i < 8; ++i) oacc[i] = (f32x4){0.f, 0.f, 0.f, 0.f};
    float m_run = -1e30f, lsum = 0.f;
    const int nt = (qB + QBLK) / 32;
    for (int t = 0; t < nt; ++t) {
        const int kv0 = t * 32;
        __syncthreads();
        {
            const int r = tid >> 3, seg = tid & 7;
            const float* src = Kg + (size_t)((b * S_ + kv0 + r) * HKV_ + hk) * D_ + seg * 16;
            float4 x0 = *(const float4*)(src + 0);
            float4 x1 = *(const float4*)(src + 4);
            float4 x2 = *(const float4*)(src + 8);
            float4 x3 = *(const float4*)(src + 12);
            uint4 u0 = { pk2(x0.x,x0.y), pk2(x0.z,x0.w), pk2(x1.x,x1.y), pk2(x1.z,x1.w) };
            uint4 u1 = { pk2(x2.x,x2.y), pk2(x2.z,x2.w), pk2(x3.x,x3.y), pk2(x3.z,x3.w) };
            const int colb = seg * 32;
            const int swz  = (r & 7) << 4;
            *(uint4*)(sK + r * 256 + ((colb     ) ^ swz)) = u0;
            *(uint4*)(sK + r * 256 + ((colb + 16) ^ swz)) = u1;
        }
        {
            const int kv = tid & 31, d0 = (tid >> 5) * 16;
            const int kp = (((kv & 15) >> 2) << 3) + ((kv >> 4) << 2) + (kv & 3);
            const float* src = Vg + (size_t)((b * S_ + kv0 + kv) * HKV_ + hk) * D_ + d0;
#pragma unroll
            for (int i = 0; i < 4; ++i) {
                float4 x = *(const float4*)(src + i * 4);
                const int d = d0 + i * 4;
                sV[(d + 0) * 40 + kp] = f2bf(x.x);
                sV[(d + 1) * 40 + kp] = f2bf(x.y);
                sV[(d + 2) * 40 + kp] = f2bf(x.z);
                sV[(d + 3) * 40 + kp] = f2bf(x.w);
            }
        }
        __syncthreads();
        if (kv0 > q0w + 15) continue;
        f32x4 st0 = (f32x4){0.f,0.f,0.f,0.f}, st1 = st0;
#pragma unroll
        for (int db = 0; db < 4; ++db) {
            const int swz = (m & 7) << 4;
            bf16x8 kf0 = *(const bf16x8*)(sK + (m      ) * 256 + ((db * 64 + g * 16) ^ swz));
            bf16x8 kf1 = *(const bf16x8*)(sK + (m + 16 ) * 256 + ((db * 64 + g * 16) ^ swz));
            st0 = __builtin_amdgcn_mfma_f32_16x16x32_bf16(kf0, qf[db], st0, 0, 0, 0);
            st1 = __builtin_amdgcn_mfma_f32_16x16x32_bf16(kf1, qf[db], st1, 0, 0, 0);
        }
        float p[8];
        float tm = -1e30f;
#pragma unroll
        for (int jj = 0; jj < 4; ++jj) {
            int kva = kv0 + g * 4 + jj;
            float s0 = (kva       <= q_abs) ? st0[jj] : -1e30f;
            float s1 = (kva + 16  <= q_abs) ? st1[jj] : -1e30f;
            p[jj]     = s0;
            p[4 + jj] = s1;
            tm = fmaxf(tm, fmaxf(s0, s1));
        }
        tm = fmaxf(tm, __shfl_xor(tm, 16));
        tm = fmaxf(tm, __shfl_xor(tm, 32));
        const float m_new = fmaxf(m_run, tm);
        const float corr  = __expf(m_run - m_new);
        float ls = 0.f;
#pragma unroll
        for (int i = 0; i < 8; ++i) { float e = __expf(p[i] - m_new); p[i] = e; ls += e; }
        ls += __shfl_xor(ls, 16);
        ls += __shfl_xor(ls, 32);
        lsum  = lsum * corr + ls;
        m_run = m_new;
        float cj[4];
#pragma unroll
        for (int jj = 0; jj < 4; ++jj) cj[jj] = __shfl(corr, g * 4 + jj);
#pragma unroll
        for (int i = 0; i < 8; ++i)
#pragma unroll
            for (int jj = 0; jj < 4; ++jj) oacc[i][jj] *= cj[jj];
        bf16x8 pa;
#pragma unroll
        for (int i = 0; i < 8; ++i) pa[i] = (short)f2bf(p[i]);
#pragma unroll
        for (int db8 = 0; db8 < 8; ++db8) {
            bf16x8 vf = *(const bf16x8*)((const unsigned char*)sV +
                          (((db8 * 16 + m) * 40 + g * 8) * 2));
            oacc[db8] = __builtin_amdgcn_mfma_f32_16x16x32_bf16(pa, vf, oacc[db8], 0, 0, 0);
        }
    }
    float rs[4];
    const float rinv = 1.0f / lsum;
#pragma unroll
    for (int jj = 0; jj < 4; ++jj) rs[jj] = __shfl(rinv, g * 4 + jj);
#pragma unroll
    for (int db8 = 0; db8 < 8; ++db8) {
#pragma unroll
        for (int jj = 0; jj < 4; ++jj) {
            const int qr = q0w + g * 4 + jj;
            Og[(size_t)((b * S_ + qr) * H_ + h) * D_ + db8 * 16 + m] = oacc[db8][jj] * rs[jj];
        }
    }
}

extern "C" void kernel_launch(void* const* d_in, const int* in_sizes, int n_in,
                              void* d_out, int out_size, void* d_ws, size_t ws_size,
                              hipStream_t stream) {
    const float* q = (const float*)d_in[0];
    const float* k = (const float*)d_in[1];
    const float* v = (const float*)d_in[2];
    float* o = (float*)d_out;

    const size_t KB_BYTES = (size_t)B_ * HKV_ * S_ * 256;             // 8 MiB
    const size_t VB_BYTES = (size_t)B_ * HKV_ * 32 * 128 * 80 * 2;    // 10 MiB

    if (ws_size >= KB_BYTES + VB_BYTES) {
        unsigned char*  Kb = (unsigned char*)d_ws;
        unsigned short* Vb = (unsigned short*)((unsigned char*)d_ws + KB_BYTES);
        prep_k<<<2048, 256, 0, stream>>>(k, Kb);
        prep_v<<<2048, 256, 0, stream>>>(v, Vb);
        fattn4<<<512, 256, 0, stream>>>(q, Kb, (const unsigned char*)Vb, o);
    } else {
        const int blocks = B_ * H_ * (S_ / QBLK);    // 2048
        fattn_fallback<<<blocks, 256, 0, stream>>>(q, k, v, o);
    }
}